// Round 3
// baseline (1145.209 us; speedup 1.0000x reference)
//
#include <hip/hip_runtime.h>
#include <math.h>

#define NB  32
#define TDS 2048
#define LL  512
#define DD  256
#define DC  64   // D/RATIO
#define GAP_THR 4e-4f

typedef __attribute__((ext_vector_type(8)))  short short8;
typedef __attribute__((ext_vector_type(16))) float f32x16;

__device__ __forceinline__ unsigned short f2bf(float x) {
    union { float f; unsigned u; } v; v.f = x;
    unsigned r = v.u + 0x7fffu + ((v.u >> 16) & 1u);
    return (unsigned short)(r >> 16);
}
__device__ __forceinline__ float bf2f(unsigned short h) {
    union { unsigned u; float f; } v; v.u = ((unsigned)h) << 16;
    return v.f;
}
__device__ __forceinline__ void gll16(const void* g, void* l) {
    __builtin_amdgcn_global_load_lds(
        (const __attribute__((address_space(1))) void*)g,
        (__attribute__((address_space(3))) void*)l, 16, 0, 0);
}

// ---------------------------------------------------------------------------
// ws layout (bytes):
//   [0, 8388608)            : KPS_HI  bf16 hi-plane of k+pe_k, swizzled image
//   [8388608, 16777216)     : KPS_LO  bf16 lo-plane
//   [16777216, 18874368)    : PEQ f32 (pe_q with w_s=1)
//   then NB*TDS ints IDX, 1 int CNT, NB*TDS ints FLAGS
// Swizzled image addressing (per plane, per b: 262144 B; per K-step ks: 32768 B):
//   element (l, k):  p = l>>1, s = ((l&1)<<2) | ((k&31)>>3), slot = s ^ (p&7)
//   byte = b*262144 + (k>>5)*32768 + p*128 + slot*16 + (k&7)*2
// ---------------------------------------------------------------------------

__global__ void init_cnt_kernel(int* __restrict__ cnt) {
    if (threadIdx.x == 0) cnt[0] = 0;
}

__global__ void peq_kernel(float* __restrict__ peq) {
    int idx = blockIdx.x * 256 + threadIdx.x;        // < TDS*DD
    int t = idx >> 8;
    int d = idx & 255;
    int i = d >> 1;
    double invdiv = exp((double)i * (-9.210340371976184 / 128.0));
    double ang = (double)t * invdiv;
    double s, c;
    sincos(ang, &s, &c);
    peq[idx] = (float)((d & 1) ? c : s);
}

// k + pe_k, split into bf16 hi/lo planes, written in the pre-swizzled image.
__global__ __launch_bounds__(256)
void pek_kernel(const float* __restrict__ k,
                const int* __restrict__ text_lengths,
                const int* __restrict__ mel_lengths,
                char* __restrict__ hi_base,
                char* __restrict__ lo_base) {
    __shared__ double invdiv[128];
    const int tid = threadIdx.x;
    if (tid < 128) invdiv[tid] = exp((double)tid * (-9.210340371976184 / 128.0));
    __syncthreads();
    int f = blockIdx.x * 256 + tid;                  // < NB*LL*32
    int b = f >> 14;
    int r = f & 16383;
    int l = r >> 5;
    int w = r & 31;
    int ks = w >> 2, g = w & 3;
    int k0 = ks * 32 + g * 8;
    const float* kr = k + ((size_t)(b * LL + l)) * DD + k0;
    float4 kv0 = *(const float4*)(kr);
    float4 kv1 = *(const float4*)(kr + 4);
    float kv[8] = {kv0.x, kv0.y, kv0.z, kv0.w, kv1.x, kv1.y, kv1.z, kv1.w};
    double wsd = ((double)mel_lengths[b] * 0.25) / (double)text_lengths[b];
    double base_ang = wsd * (double)l;
    unsigned short h[8], lo8[8];
#pragma unroll
    for (int jj = 0; jj < 4; ++jj) {
        int i = (k0 >> 1) + jj;
        double ang = base_ang * invdiv[i];
        double n = rint(ang * 0.15915494309189535);
        double red = fma(n, -6.283185307179586, ang);   // |red| <= pi
        float sn, cs;
        sincosf((float)red, &sn, &cs);
        float e0 = kv[2 * jj] + sn;
        float e1 = kv[2 * jj + 1] + cs;
        h[2 * jj]     = f2bf(e0);
        h[2 * jj + 1] = f2bf(e1);
        lo8[2 * jj]     = f2bf(e0 - bf2f(h[2 * jj]));
        lo8[2 * jj + 1] = f2bf(e1 - bf2f(h[2 * jj + 1]));
    }
    int p = l >> 1;
    int s = ((l & 1) << 2) | g;
    int slot = s ^ (p & 7);
    size_t off = (size_t)b * 262144 + (size_t)ks * 32768 + p * 128 + slot * 16;
    uint4 hv, lv;
    hv.x = h[0] | ((unsigned)h[1] << 16); hv.y = h[2] | ((unsigned)h[3] << 16);
    hv.z = h[4] | ((unsigned)h[5] << 16); hv.w = h[6] | ((unsigned)h[7] << 16);
    lv.x = lo8[0] | ((unsigned)lo8[1] << 16); lv.y = lo8[2] | ((unsigned)lo8[3] << 16);
    lv.z = lo8[4] | ((unsigned)lo8[5] << 16); lv.w = lo8[6] | ((unsigned)lo8[7] << 16);
    *(uint4*)(hi_base + off) = hv;
    *(uint4*)(lo_base + off) = lv;
}

// ---------------------------------------------------------------------------
// score kernel: 64 t-rows x 512 l-cols per block via split-bf16 MFMA.
// 8 waves: wm = wid>>2 (32-row tile), wn = wid&3 (128-col tile).
// ---------------------------------------------------------------------------
__global__ __launch_bounds__(512, 2)
void score_kernel(const float* __restrict__ q,
                  const float* __restrict__ peq,
                  const char* __restrict__ kps_hi,
                  const char* __restrict__ kps_lo,
                  const int* __restrict__ text_lengths,
                  const int* __restrict__ mel_lengths,
                  float* __restrict__ align_out,
                  int* __restrict__ idx_out,
                  int* __restrict__ flag_cnt,
                  int* __restrict__ flags) {
    // per buf (73728 B): [Bhi 32768][Blo 32768][Ahi 4096][Alo 4096]
    __shared__ alignas(16) char smbuf[2 * 73728];
    __shared__ float smv1[4][64];
    __shared__ int   smi1[4][64];
    __shared__ float smv2[4][64];
    __shared__ float smS[4][64];
    __shared__ float smM[64];

    const int wgid = blockIdx.x;
    const int xcd = wgid & 7, loc = wgid >> 3;
    const int nid = xcd * 128 + loc;        // XCD-contiguous: 4 b's per XCD
    const int b = nid >> 5;
    const int t0 = (nid & 31) * 64;

    const int tid = threadIdx.x;
    const int wid = tid >> 6, lane = tid & 63;
    const int wm = wid >> 2, wn = wid & 3;
    const int c31 = lane & 31, hi5 = lane >> 5;
    const int tlen = text_lengths[b];
    const int melq = mel_lengths[b] >> 2;

    const char* khb = kps_hi + (size_t)b * 262144;
    const char* klb = kps_lo + (size_t)b * 262144;
    char* sm = smbuf;

    f32x16 acc[4];
#pragma unroll
    for (int nt = 0; nt < 4; ++nt)
#pragma unroll
        for (int rg = 0; rg < 16; ++rg) acc[nt][rg] = 0.f;

    const int srow = tid >> 3, sgq = tid & 7;   // A staging assignment
    const float* qrow = q + ((size_t)(b * TDS + t0 + srow)) * DD + sgq * 4;
    const float* prow = peq + ((size_t)(t0 + srow)) * DD + sgq * 4;
    const int sA0 = ((srow & 1) << 2) + (sgq >> 1);
    const int aoffW = ((srow >> 1) << 7) + (((sA0) ^ ((srow >> 1) & 7)) << 4) + ((sgq & 1) << 3);

    // A frag read offsets (per kh)
    const int rowA = wm * 32 + c31;
    const int g2 = hi5;
    int aro[2], bro[4][2];
#pragma unroll
    for (int kh = 0; kh < 2; ++kh) {
        int sA = ((rowA & 1) << 2) + kh * 2 + g2;
        aro[kh] = ((rowA >> 1) << 7) + ((sA ^ ((rowA >> 1) & 7)) << 4);
#pragma unroll
        for (int nt = 0; nt < 4; ++nt) {
            int l = wn * 128 + nt * 32 + c31;
            int sB = ((l & 1) << 2) + kh * 2 + g2;
            bro[nt][kh] = ((l >> 1) << 7) + ((sB ^ ((l >> 1) & 7)) << 4);
        }
    }

#define STAGE_B(buf, ks)                                                        \
    {                                                                           \
        const char* s_h = khb + (ks) * 32768 + wid * 1024 + (lane << 4);        \
        const char* s_l = klb + (ks) * 32768 + wid * 1024 + (lane << 4);        \
        char* d_h = sm + (buf) * 73728 + wid * 1024;                            \
        char* d_l = sm + (buf) * 73728 + 32768 + wid * 1024;                    \
        gll16(s_h, d_h); gll16(s_h + 8192, d_h + 8192);                         \
        gll16(s_h + 16384, d_h + 16384); gll16(s_h + 24576, d_h + 24576);       \
        gll16(s_l, d_l); gll16(s_l + 8192, d_l + 8192);                         \
        gll16(s_l + 16384, d_l + 16384); gll16(s_l + 24576, d_l + 24576);       \
    }

    // ---- prologue: stage ks=0 ----
    STAGE_B(0, 0)
    {
        float4 qv = *(const float4*)(qrow);
        float4 pv = *(const float4*)(prow);
        float a0 = (qv.x + pv.x) * 0.0625f, a1 = (qv.y + pv.y) * 0.0625f;
        float a2 = (qv.z + pv.z) * 0.0625f, a3 = (qv.w + pv.w) * 0.0625f;
        unsigned short h0 = f2bf(a0), h1 = f2bf(a1), h2 = f2bf(a2), h3 = f2bf(a3);
        unsigned short u0 = f2bf(a0 - bf2f(h0)), u1 = f2bf(a1 - bf2f(h1));
        unsigned short u2 = f2bf(a2 - bf2f(h2)), u3 = f2bf(a3 - bf2f(h3));
        uint2 hv = {h0 | ((unsigned)h1 << 16), h2 | ((unsigned)h3 << 16)};
        uint2 lv = {u0 | ((unsigned)u1 << 16), u2 | ((unsigned)u3 << 16)};
        *(uint2*)(sm + 65536 + aoffW) = hv;
        *(uint2*)(sm + 69632 + aoffW) = lv;
    }
    __syncthreads();

    for (int ks = 0; ks < 8; ++ks) {
        const int cur = ks & 1;
        const char* base = sm + cur * 73728;
        float4 qv, pv;
        if (ks < 7) {
            STAGE_B(cur ^ 1, ks + 1)
            qv = *(const float4*)(qrow + (ks + 1) * 32);
            pv = *(const float4*)(prow + (ks + 1) * 32);
        }
#pragma unroll
        for (int kh = 0; kh < 2; ++kh) {
            short8 ah = *(const short8*)(base + 65536 + aro[kh]);
            short8 al = *(const short8*)(base + 69632 + aro[kh]);
#pragma unroll
            for (int nt = 0; nt < 4; ++nt) {
                short8 bh = *(const short8*)(base + bro[nt][kh]);
                short8 bl = *(const short8*)(base + 32768 + bro[nt][kh]);
                acc[nt] = __builtin_amdgcn_mfma_f32_32x32x16_bf16(ah, bh, acc[nt], 0, 0, 0);
                acc[nt] = __builtin_amdgcn_mfma_f32_32x32x16_bf16(ah, bl, acc[nt], 0, 0, 0);
                acc[nt] = __builtin_amdgcn_mfma_f32_32x32x16_bf16(al, bh, acc[nt], 0, 0, 0);
            }
        }
        if (ks < 7) {   // write A for next step after this step's LDS reads
            float a0 = (qv.x + pv.x) * 0.0625f, a1 = (qv.y + pv.y) * 0.0625f;
            float a2 = (qv.z + pv.z) * 0.0625f, a3 = (qv.w + pv.w) * 0.0625f;
            unsigned short h0 = f2bf(a0), h1 = f2bf(a1), h2 = f2bf(a2), h3 = f2bf(a3);
            unsigned short u0 = f2bf(a0 - bf2f(h0)), u1 = f2bf(a1 - bf2f(h1));
            unsigned short u2 = f2bf(a2 - bf2f(h2)), u3 = f2bf(a3 - bf2f(h3));
            uint2 hv = {h0 | ((unsigned)h1 << 16), h2 | ((unsigned)h3 << 16)};
            uint2 lv = {u0 | ((unsigned)u1 << 16), u2 | ((unsigned)u3 << 16)};
            char* nb = sm + (cur ^ 1) * 73728;
            *(uint2*)(nb + 65536 + aoffW) = hv;
            *(uint2*)(nb + 69632 + aoffW) = lv;
        }
        __syncthreads();
    }

    // ---- epilogue: mask, top-2, softmax, stores ----
    const float NEGINF = -__builtin_inff();
    const int colbase = wn * 128 + c31;
#pragma unroll
    for (int nt = 0; nt < 4; ++nt) {
        int col = colbase + nt * 32;
        if (col >= tlen) {
#pragma unroll
            for (int rg = 0; rg < 16; ++rg) acc[nt][rg] = NEGINF;
        }
    }
    float v1[16]; int i1[16]; float v2[16];
#pragma unroll
    for (int rg = 0; rg < 16; ++rg) {
        v1[rg] = acc[0][rg]; i1[rg] = colbase; v2[rg] = NEGINF;
#pragma unroll
        for (int nt = 1; nt < 4; ++nt) {
            float v = acc[nt][rg]; int col = colbase + nt * 32;
            if (v > v1[rg]) { v2[rg] = v1[rg]; v1[rg] = v; i1[rg] = col; }
            else if (v > v2[rg]) v2[rg] = v;
        }
    }
#pragma unroll
    for (int off = 1; off <= 16; off <<= 1) {
#pragma unroll
        for (int rg = 0; rg < 16; ++rg) {
            float ov1 = __shfl_xor(v1[rg], off, 64);
            int   oi1 = __shfl_xor(i1[rg], off, 64);
            float ov2 = __shfl_xor(v2[rg], off, 64);
            if (ov1 > v1[rg]) { v2[rg] = fmaxf(v1[rg], ov2); v1[rg] = ov1; i1[rg] = oi1; }
            else if (ov1 < v1[rg]) { v2[rg] = fmaxf(v2[rg], ov1); }
            else { i1[rg] = min(i1[rg], oi1); v2[rg] = v1[rg]; }
        }
    }
    if (c31 == 0) {
#pragma unroll
        for (int rg = 0; rg < 16; ++rg) {
            int r64 = wm * 32 + (rg & 3) + 8 * (rg >> 2) + 4 * hi5;
            smv1[wn][r64] = v1[rg]; smi1[wn][r64] = i1[rg]; smv2[wn][r64] = v2[rg];
        }
    }
    __syncthreads();
    {
        const int r64 = wm * 32 + c31;
        float V1 = smv1[0][r64]; int I1 = smi1[0][r64]; float V2 = smv2[0][r64];
#pragma unroll
        for (int w = 1; w < 4; ++w) {
            float cv1 = smv1[w][r64]; int ci1 = smi1[w][r64]; float cv2 = smv2[w][r64];
            if (cv1 > V1) { V2 = fmaxf(V1, cv2); V1 = cv1; I1 = ci1; }
            else if (cv1 < V1) { V2 = fmaxf(V2, cv1); }
            else { V2 = V1; }
        }
        if (wn == 0 && hi5 == 0) {
            int t = t0 + r64;
            idx_out[b * TDS + t] = I1;
            if (t < melq && (V1 - V2) < GAP_THR) {
                int pos = atomicAdd(flag_cnt, 1);
                flags[pos] = (b << 11) | t;
            }
            smM[r64] = V1;
        }
    }
    __syncthreads();
    float ssum[16];
#pragma unroll
    for (int rg = 0; rg < 16; ++rg) {
        int rr = wm * 32 + (rg & 3) + 8 * (rg >> 2) + 4 * hi5;
        float M = smM[rr];
        float s = 0.f;
#pragma unroll
        for (int nt = 0; nt < 4; ++nt) {
            float p = __expf(acc[nt][rg] - M);
            acc[nt][rg] = p; s += p;
        }
        ssum[rg] = s;
    }
#pragma unroll
    for (int off = 1; off <= 16; off <<= 1)
#pragma unroll
        for (int rg = 0; rg < 16; ++rg) ssum[rg] += __shfl_xor(ssum[rg], off, 64);
    if (c31 == 0) {
#pragma unroll
        for (int rg = 0; rg < 16; ++rg) {
            int rr = wm * 32 + (rg & 3) + 8 * (rg >> 2) + 4 * hi5;
            smS[wn][rr] = ssum[rg];
        }
    }
    __syncthreads();
#pragma unroll
    for (int rg = 0; rg < 16; ++rg) {
        int rr = wm * 32 + (rg & 3) + 8 * (rg >> 2) + 4 * hi5;
        int t = t0 + rr;
        float denom = smS[0][rr] + smS[1][rr] + smS[2][rr] + smS[3][rr];
        float sc = (t < melq) ? (1.0f / denom) : 0.f;
        size_t obase = ((size_t)(b * TDS + t)) * LL + colbase;
#pragma unroll
        for (int nt = 0; nt < 4; ++nt)
            align_out[obase + nt * 32] = acc[nt][rg] * sc;
    }
#undef STAGE_B
}

// ---------------------------------------------------------------------------
// refine kernel: recompute flagged rows' 512 scores fully in f64, fix idx.
// ---------------------------------------------------------------------------
__global__ __launch_bounds__(256)
void refine_kernel(const float* __restrict__ q,
                   const float* __restrict__ k,
                   const int* __restrict__ text_lengths,
                   const int* __restrict__ mel_lengths,
                   const int* __restrict__ flags,
                   const int* __restrict__ flag_cnt,
                   int* __restrict__ idx_out) {
    __shared__ double qd[DD];
    __shared__ double invdiv[128];
    __shared__ double rbest[4];
    __shared__ int    ribest[4];
    const int tid = threadIdx.x;
    if (tid < 128)
        invdiv[tid] = 1.0 / pow(10000.0, (double)tid * (1.0 / 128.0));
    const int cnt = flag_cnt[0];
    for (int r = blockIdx.x; r < cnt; r += gridDim.x) {
        const int code = flags[r];
        const int b = code >> 11, t = code & 2047;
        const int tlen = text_lengths[b];
        const double ws = ((double)mel_lengths[b] * 0.25) / (double)text_lengths[b];
        __syncthreads();
        {
            const int d = tid, i = d >> 1;
            double ang = (double)t * invdiv[i];
            double sn, cs;
            sincos(ang, &sn, &cs);
            qd[d] = ((double)q[((size_t)b * TDS + t) * DD + d] + ((d & 1) ? cs : sn)) * 0.0625;
        }
        __syncthreads();
        double best = -1.0e300; int bi = 0x7fffffff;
        for (int p = 0; p < 2; ++p) {
            const int l = tid + p * 256;
            if (l < tlen) {
                const float* kr = k + ((size_t)b * LL + l) * DD;
                const double wl = ws * (double)l;
                double sacc = 0.0;
                for (int i = 0; i < 128; ++i) {
                    double ang = wl * invdiv[i];
                    double sn, cs;
                    sincos(ang, &sn, &cs);
                    sacc += ((double)kr[2 * i]     + sn) * qd[2 * i];
                    sacc += ((double)kr[2 * i + 1] + cs) * qd[2 * i + 1];
                }
                if (sacc > best || (sacc == best && l < bi)) { best = sacc; bi = l; }
            }
        }
        for (int off = 1; off <= 32; off <<= 1) {
            double ov = __shfl_xor(best, off, 64);
            int   oi = __shfl_xor(bi, off, 64);
            if (ov > best || (ov == best && oi < bi)) { best = ov; bi = oi; }
        }
        const int wv = tid >> 6;
        if ((tid & 63) == 0) { rbest[wv] = best; ribest[wv] = bi; }
        __syncthreads();
        if (tid == 0) {
            double bb = rbest[0]; int ii = ribest[0];
            for (int w = 1; w < 4; ++w)
                if (rbest[w] > bb || (rbest[w] == bb && ribest[w] < ii)) { bb = rbest[w]; ii = ribest[w]; }
            idx_out[b * TDS + t] = ii;
        }
    }
}

// ---------------------------------------------------------------------------
// compress kernel: out[b,c,t] = sum_d w[c,d] * v[b, idx[b,t], d] (0 if masked)
// ---------------------------------------------------------------------------
__global__ __launch_bounds__(256, 4)
void compress_kernel(const float* __restrict__ v,
                     const float* __restrict__ wc,
                     const int* __restrict__ idx_in,
                     const int* __restrict__ mel_lengths,
                     float* __restrict__ out) {
    __shared__ float Ws[256 * 68];
    __shared__ float Vs[16 * 132];
    __shared__ int   idxs[128];
    const int b   = blockIdx.y;
    const int t0  = blockIdx.x * 128;
    const int tid = threadIdx.x;
    const int melq = mel_lengths[b] >> 2;
    const float* vb = v + (size_t)b * LL * DD;

    if (tid < 128) {
        int t = t0 + tid;
        int ii = idx_in[b * TDS + t];
        idxs[tid] = (t >= melq) ? -1 : ii;
    }
#pragma unroll
    for (int r = 0; r < 16; ++r) {
        int f = tid + r * 256;
        int c = f >> 6;
        int u = f & 63;
        float4 wv = *(const float4*)(wc + (size_t)c * DD + u * 4);
        Ws[(u * 4 + 0) * 68 + c] = wv.x;
        Ws[(u * 4 + 1) * 68 + c] = wv.y;
        Ws[(u * 4 + 2) * 68 + c] = wv.z;
        Ws[(u * 4 + 3) * 68 + c] = wv.w;
    }

    const int tx = tid & 7;
    const int ty = tid >> 3;
    const int tv = tid >> 2;
    const int uv = tid & 3;
    float acc[8][4];
#pragma unroll
    for (int i = 0; i < 8; ++i)
#pragma unroll
        for (int j = 0; j < 4; ++j) acc[i][j] = 0.f;

    for (int ks = 0; ks < 16; ++ks) {
        const int d0 = ks * 16;
        __syncthreads();
#pragma unroll
        for (int p = 0; p < 2; ++p) {
            int t = tv + p * 64;
            int row = idxs[t];
            float4 vv = make_float4(0.f, 0.f, 0.f, 0.f);
            if (row >= 0) vv = *(const float4*)(vb + (size_t)row * DD + d0 + uv * 4);
            Vs[(uv * 4 + 0) * 132 + t] = vv.x;
            Vs[(uv * 4 + 1) * 132 + t] = vv.y;
            Vs[(uv * 4 + 2) * 132 + t] = vv.z;
            Vs[(uv * 4 + 3) * 132 + t] = vv.w;
        }
        __syncthreads();
#pragma unroll
        for (int kk = 0; kk < 16; ++kk) {
            const float* wrow = Ws + (size_t)(d0 + kk) * 68 + tx * 8;
            float4 a0 = *(const float4*)(wrow);
            float4 a1 = *(const float4*)(wrow + 4);
            float4 bb = *(const float4*)(Vs + kk * 132 + ty * 4);
            const float av[8] = {a0.x, a0.y, a0.z, a0.w, a1.x, a1.y, a1.z, a1.w};
            const float bv[4] = {bb.x, bb.y, bb.z, bb.w};
#pragma unroll
            for (int i = 0; i < 8; ++i)
#pragma unroll
                for (int j = 0; j < 4; ++j)
                    acc[i][j] = fmaf(av[i], bv[j], acc[i][j]);
        }
    }
#pragma unroll
    for (int ci = 0; ci < 8; ++ci) {
        int c = tx * 8 + ci;
        float4 o;
        o.x = acc[ci][0]; o.y = acc[ci][1]; o.z = acc[ci][2]; o.w = acc[ci][3];
        *(float4*)(out + ((size_t)(b * DC + c)) * TDS + t0 + ty * 4) = o;
    }
}

extern "C" void kernel_launch(void* const* d_in, const int* in_sizes, int n_in,
                              void* d_out, int out_size, void* d_ws, size_t ws_size,
                              hipStream_t stream) {
    const float* q    = (const float*)d_in[0];
    const float* k    = (const float*)d_in[1];
    const float* v    = (const float*)d_in[2];
    const float* wc   = (const float*)d_in[3];
    const int*   text = (const int*)d_in[4];
    const int*   mel  = (const int*)d_in[5];

    float* out   = (float*)d_out;
    float* align = out + (size_t)NB * DC * TDS;

    char*  wsb = (char*)d_ws;
    char*  KPS_HI = wsb;
    char*  KPS_LO = wsb + 8388608;
    float* PEQ = (float*)(wsb + 16777216);
    int*   IDX = (int*)(wsb + 16777216 + 2097152);
    int*   CNT = IDX + (size_t)NB * TDS;
    int*   FLG = CNT + 1;

    hipLaunchKernelGGL(init_cnt_kernel, dim3(1), dim3(64), 0, stream, CNT);
    hipLaunchKernelGGL(peq_kernel, dim3(TDS * DD / 256), dim3(256), 0, stream, PEQ);
    hipLaunchKernelGGL(pek_kernel, dim3(NB * LL * 32 / 256), dim3(256), 0, stream,
                       k, text, mel, KPS_HI, KPS_LO);
    hipLaunchKernelGGL(score_kernel, dim3(1024), dim3(512), 0, stream,
                       q, PEQ, KPS_HI, KPS_LO, text, mel, align, IDX, CNT, FLG);
    hipLaunchKernelGGL(refine_kernel, dim3(128), dim3(256), 0, stream,
                       q, k, text, mel, FLG, CNT, IDX);
    hipLaunchKernelGGL(compress_kernel, dim3(TDS / 128, NB), dim3(256), 0, stream,
                       v, wc, IDX, mel, out);
}

// Round 4
// 245.060 us; speedup vs baseline: 4.6732x; 4.6732x over previous
//
#include <hip/hip_runtime.h>
#include <math.h>

#define NB  32
#define TDS 2048
#define LL  512
#define DD  256
#define DC  64   // D/RATIO
#define GAP_THR 4e-4f

typedef __attribute__((ext_vector_type(8)))  short short8;
typedef __attribute__((ext_vector_type(16))) float f32x16;

__device__ __forceinline__ unsigned short f2bf(float x) {
    union { float f; unsigned u; } v; v.f = x;
    unsigned r = v.u + 0x7fffu + ((v.u >> 16) & 1u);
    return (unsigned short)(r >> 16);
}
__device__ __forceinline__ float bf2f(unsigned short h) {
    union { unsigned u; float f; } v; v.u = ((unsigned)h) << 16;
    return v.f;
}
__device__ __forceinline__ void gll16(const void* g, void* l) {
    __builtin_amdgcn_global_load_lds(
        (const __attribute__((address_space(1))) void*)g,
        (__attribute__((address_space(3))) void*)l, 16, 0, 0);
}
__device__ __forceinline__ int swz3(int x) { return (x & 7) ^ ((x >> 3) & 7); }

// ---------------------------------------------------------------------------
// ws layout (bytes):
//   [0, 8388608)            : KPS_HI  bf16 hi-plane of k+pe_k, swizzled image
//   [8388608, 16777216)     : KPS_LO  bf16 lo-plane
//   [16777216, 18874368)    : PEQ f32 (pe_q with w_s=1)
//   then NB*TDS ints IDX, 1 int CNT, NB*TDS ints FLAGS
// KPS image: per b per plane 262144 B = [ks 0..7][lt 0..3] tiles of 8192 B.
//   tile element (c 0..127, kk 0..31): byte = (c*64 + kk*2) ^ (swz3(c)<<4)
// ---------------------------------------------------------------------------

__global__ void init_cnt_kernel(int* __restrict__ cnt) {
    if (threadIdx.x == 0) cnt[0] = 0;
}

__global__ void peq_kernel(float* __restrict__ peq) {
    int idx = blockIdx.x * 256 + threadIdx.x;        // < TDS*DD
    int t = idx >> 8;
    int d = idx & 255;
    int i = d >> 1;
    double invdiv = exp((double)i * (-9.210340371976184 / 128.0));
    double ang = (double)t * invdiv;
    double s, c;
    sincos(ang, &s, &c);
    peq[idx] = (float)((d & 1) ? c : s);
}

// k + pe_k, split into bf16 hi/lo planes, written in the tiled+swizzled image.
__global__ __launch_bounds__(256)
void pek_kernel(const float* __restrict__ k,
                const int* __restrict__ text_lengths,
                const int* __restrict__ mel_lengths,
                char* __restrict__ hi_base,
                char* __restrict__ lo_base) {
    __shared__ double invdiv[128];
    const int tid = threadIdx.x;
    if (tid < 128) invdiv[tid] = exp((double)tid * (-9.210340371976184 / 128.0));
    __syncthreads();
    int f = blockIdx.x * 256 + tid;                  // < NB*512*32
    int b = f >> 14;
    int r = f & 16383;
    int ks = r >> 11;
    int rr = r & 2047;
    int lt = rr >> 9;
    int r2 = rr & 511;
    int c  = r2 >> 2;
    int ch = r2 & 3;
    int l  = lt * 128 + c;
    int kk = ks * 32 + ch * 8;
    const float* kr = k + ((size_t)(b * LL + l)) * DD + kk;
    float4 kv0 = *(const float4*)(kr);
    float4 kv1 = *(const float4*)(kr + 4);
    float kv[8] = {kv0.x, kv0.y, kv0.z, kv0.w, kv1.x, kv1.y, kv1.z, kv1.w};
    double wsd = ((double)mel_lengths[b] * 0.25) / (double)text_lengths[b];
    double base_ang = wsd * (double)l;
    unsigned short h[8], lo8[8];
#pragma unroll
    for (int jj = 0; jj < 4; ++jj) {
        int i = (kk >> 1) + jj;
        double ang = base_ang * invdiv[i];
        double n = rint(ang * 0.15915494309189535);
        double red = fma(n, -6.283185307179586, ang);   // |red| <= pi
        float sn, cs;
        sincosf((float)red, &sn, &cs);
        float e0 = kv[2 * jj] + sn;
        float e1 = kv[2 * jj + 1] + cs;
        h[2 * jj]       = f2bf(e0);
        h[2 * jj + 1]   = f2bf(e1);
        lo8[2 * jj]     = f2bf(e0 - bf2f(h[2 * jj]));
        lo8[2 * jj + 1] = f2bf(e1 - bf2f(h[2 * jj + 1]));
    }
    size_t off = (size_t)b * 262144 + (size_t)(ks * 4 + lt) * 8192
               + (size_t)((c * 64 + ch * 16) ^ (swz3(c) << 4));
    uint4 hv, lv;
    hv.x = h[0] | ((unsigned)h[1] << 16); hv.y = h[2] | ((unsigned)h[3] << 16);
    hv.z = h[4] | ((unsigned)h[5] << 16); hv.w = h[6] | ((unsigned)h[7] << 16);
    lv.x = lo8[0] | ((unsigned)lo8[1] << 16); lv.y = lo8[2] | ((unsigned)lo8[3] << 16);
    lv.z = lo8[4] | ((unsigned)lo8[5] << 16); lv.w = lo8[6] | ((unsigned)lo8[7] << 16);
    *(uint4*)(hi_base + off) = hv;
    *(uint4*)(lo_base + off) = lv;
}

// ---------------------------------------------------------------------------
// score kernel: 64 t-rows x 512 l-cols per block via split-bf16 MFMA 32x32x16.
// 8 waves: wm = wid>>2 (32-row half), wn = wid&3 (32-col slot in each lt tile).
// lt loop: 4 x 128-col B tiles, double-buffered 16KB; A 8KB double-buffered.
// ---------------------------------------------------------------------------
__global__ __launch_bounds__(512, 4)
void score_kernel(const float* __restrict__ q,
                  const float* __restrict__ peq,
                  const char* __restrict__ kps_hi,
                  const char* __restrict__ kps_lo,
                  const int* __restrict__ text_lengths,
                  const int* __restrict__ mel_lengths,
                  float* __restrict__ align_out,
                  int* __restrict__ idx_out,
                  int* __restrict__ flag_cnt,
                  int* __restrict__ flags) {
    __shared__ alignas(16) char smB[2 * 16384];   // per buf: [hi 8KB][lo 8KB]
    __shared__ alignas(16) char smA[2 * 8192];    // per buf: [hi 4KB][lo 4KB]
    __shared__ float smv1[4][64];
    __shared__ int   smi1[4][64];
    __shared__ float smv2[4][64];
    __shared__ float smS[4][64];
    __shared__ float smM[64];

    const int wgid = blockIdx.x;
    const int xcd = wgid & 7, loc = wgid >> 3;
    const int nid = xcd * 128 + loc;        // XCD-contiguous: 4 b's per XCD
    const int b = nid >> 5;
    const int t0 = (nid & 31) * 64;

    const int tid = threadIdx.x;
    const int wid = tid >> 6, lane = tid & 63;
    const int wm = wid >> 2, wn = wid & 3;
    const int c31 = lane & 31, hi5 = lane >> 5;
    const int tlen = text_lengths[b];
    const int melq = mel_lengths[b] >> 2;

    const char* khb = kps_hi + (size_t)b * 262144;
    const char* klb = kps_lo + (size_t)b * 262144;

    f32x16 acc[4];
#pragma unroll
    for (int lt = 0; lt < 4; ++lt)
#pragma unroll
        for (int rg = 0; rg < 16; ++rg) acc[lt][rg] = 0.f;

    // fragment read offsets (2-way max bank conflict via XOR swizzle)
    const int rowA = wm * 32 + c31;
    const int cB   = wn * 32 + c31;
    int aoff[2], boff[2];
#pragma unroll
    for (int kh = 0; kh < 2; ++kh) {
        aoff[kh] = (rowA * 64 + kh * 32 + hi5 * 16) ^ (swz3(rowA) << 4);
        boff[kh] = (cB   * 64 + kh * 32 + hi5 * 16) ^ (swz3(cB)   << 4);
    }

    // A staging assignment: thread -> (row, 4 k-elems)
    const int sr  = tid >> 3;
    const int sk0 = (tid & 7) * 4;
    const float* qrow = q   + ((size_t)(b * TDS + t0 + sr)) * DD + sk0;
    const float* prow = peq + ((size_t)(t0 + sr)) * DD + sk0;
    const int awaddr = (sr * 64 + sk0 * 2) ^ (swz3(sr) << 4);

#define STAGE_B(bbuf, ksv, ltv)                                                 \
    {                                                                           \
        const size_t toff = (size_t)(((ksv) * 4 + (ltv)) * 8192) + tid * 16;    \
        gll16(khb + toff, smB + (bbuf) * 16384 + tid * 16);                     \
        gll16(klb + toff, smB + (bbuf) * 16384 + 8192 + tid * 16);              \
    }
#define STAGE_A(abuf, ksv)                                                      \
    {                                                                           \
        float4 qv = *(const float4*)(qrow + (ksv) * 32);                        \
        float4 pv = *(const float4*)(prow + (ksv) * 32);                        \
        float a0 = (qv.x + pv.x) * 0.0625f, a1 = (qv.y + pv.y) * 0.0625f;       \
        float a2 = (qv.z + pv.z) * 0.0625f, a3 = (qv.w + pv.w) * 0.0625f;       \
        unsigned short h0 = f2bf(a0), h1 = f2bf(a1), h2 = f2bf(a2), h3 = f2bf(a3); \
        ushort4 hv = {h0, h1, h2, h3};                                          \
        ushort4 lv = {f2bf(a0 - bf2f(h0)), f2bf(a1 - bf2f(h1)),                 \
                      f2bf(a2 - bf2f(h2)), f2bf(a3 - bf2f(h3))};                \
        *(ushort4*)(smA + (abuf) * 8192 + awaddr) = hv;                         \
        *(ushort4*)(smA + (abuf) * 8192 + 4096 + awaddr) = lv;                  \
    }

    // prologue
    STAGE_B(0, 0, 0)
    STAGE_A(0, 0)
    __syncthreads();

    for (int ks = 0; ks < 8; ++ks) {
        const int ab = ks & 1;
        short8 ah[2], al[2];
#pragma unroll
        for (int kh = 0; kh < 2; ++kh) {
            ah[kh] = *(const short8*)(smA + ab * 8192 + aoff[kh]);
            al[kh] = *(const short8*)(smA + ab * 8192 + 4096 + aoff[kh]);
        }
#pragma unroll
        for (int lt = 0; lt < 4; ++lt) {
            const int bb = lt & 1;
            if (lt < 3) {
                STAGE_B(bb ^ 1, ks, lt + 1)
            } else if (ks < 7) {
                STAGE_B(bb ^ 1, ks + 1, 0)
                STAGE_A(ab ^ 1, ks + 1)
            }
#pragma unroll
            for (int kh = 0; kh < 2; ++kh) {
                short8 bh = *(const short8*)(smB + bb * 16384 + boff[kh]);
                short8 bl = *(const short8*)(smB + bb * 16384 + 8192 + boff[kh]);
                acc[lt] = __builtin_amdgcn_mfma_f32_32x32x16_bf16(ah[kh], bh, acc[lt], 0, 0, 0);
                acc[lt] = __builtin_amdgcn_mfma_f32_32x32x16_bf16(ah[kh], bl, acc[lt], 0, 0, 0);
                acc[lt] = __builtin_amdgcn_mfma_f32_32x32x16_bf16(al[kh], bh, acc[lt], 0, 0, 0);
            }
            __syncthreads();
        }
    }
#undef STAGE_B
#undef STAGE_A

    // ---- epilogue: mask, top-2, softmax, stores (32x32 C layout:
    //      col = lane&31 (within 32-col slot), row = (rg&3)+8*(rg>>2)+4*hi5) ----
    const float NEGINF = -__builtin_inff();
#pragma unroll
    for (int lt = 0; lt < 4; ++lt) {
        int col = lt * 128 + cB;
        if (col >= tlen) {
#pragma unroll
            for (int rg = 0; rg < 16; ++rg) acc[lt][rg] = NEGINF;
        }
    }
    float v1[16]; int i1[16]; float v2[16];
#pragma unroll
    for (int rg = 0; rg < 16; ++rg) {
        v1[rg] = acc[0][rg]; i1[rg] = cB; v2[rg] = NEGINF;
#pragma unroll
        for (int lt = 1; lt < 4; ++lt) {
            float v = acc[lt][rg]; int col = lt * 128 + cB;
            if (v > v1[rg]) { v2[rg] = v1[rg]; v1[rg] = v; i1[rg] = col; }
            else if (v > v2[rg]) v2[rg] = v;
        }
    }
#pragma unroll
    for (int off = 1; off <= 16; off <<= 1) {
#pragma unroll
        for (int rg = 0; rg < 16; ++rg) {
            float ov1 = __shfl_xor(v1[rg], off, 64);
            int   oi1 = __shfl_xor(i1[rg], off, 64);
            float ov2 = __shfl_xor(v2[rg], off, 64);
            if (ov1 > v1[rg]) { v2[rg] = fmaxf(v1[rg], ov2); v1[rg] = ov1; i1[rg] = oi1; }
            else if (ov1 < v1[rg]) { v2[rg] = fmaxf(v2[rg], ov1); }
            else { i1[rg] = min(i1[rg], oi1); v2[rg] = v1[rg]; }
        }
    }
    if (c31 == 0) {
#pragma unroll
        for (int rg = 0; rg < 16; ++rg) {
            int r64 = wm * 32 + (rg & 3) + 8 * (rg >> 2) + 4 * hi5;
            smv1[wn][r64] = v1[rg]; smi1[wn][r64] = i1[rg]; smv2[wn][r64] = v2[rg];
        }
    }
    __syncthreads();
    {
        const int r64 = wm * 32 + c31;
        float V1 = smv1[0][r64]; int I1 = smi1[0][r64]; float V2 = smv2[0][r64];
#pragma unroll
        for (int w = 1; w < 4; ++w) {
            float cv1 = smv1[w][r64]; int ci1 = smi1[w][r64]; float cv2 = smv2[w][r64];
            if (cv1 > V1) { V2 = fmaxf(V1, cv2); V1 = cv1; I1 = ci1; }
            else if (cv1 < V1) { V2 = fmaxf(V2, cv1); }
            else { V2 = V1; }
        }
        if (wn == 0 && hi5 == 0) {
            int t = t0 + r64;
            idx_out[b * TDS + t] = I1;
            if (t < melq && (V1 - V2) < GAP_THR) {
                int pos = atomicAdd(flag_cnt, 1);
                flags[pos] = (b << 11) | t;
            }
            smM[r64] = V1;
        }
    }
    __syncthreads();
    float ssum[16];
#pragma unroll
    for (int rg = 0; rg < 16; ++rg) {
        int rr = wm * 32 + (rg & 3) + 8 * (rg >> 2) + 4 * hi5;
        float M = smM[rr];
        float s = 0.f;
#pragma unroll
        for (int lt = 0; lt < 4; ++lt) {
            float p = __expf(acc[lt][rg] - M);
            acc[lt][rg] = p; s += p;
        }
        ssum[rg] = s;
    }
#pragma unroll
    for (int off = 1; off <= 16; off <<= 1)
#pragma unroll
        for (int rg = 0; rg < 16; ++rg) ssum[rg] += __shfl_xor(ssum[rg], off, 64);
    if (c31 == 0) {
#pragma unroll
        for (int rg = 0; rg < 16; ++rg) {
            int rr = wm * 32 + (rg & 3) + 8 * (rg >> 2) + 4 * hi5;
            smS[wn][rr] = ssum[rg];
        }
    }
    __syncthreads();
#pragma unroll
    for (int rg = 0; rg < 16; ++rg) {
        int rr = wm * 32 + (rg & 3) + 8 * (rg >> 2) + 4 * hi5;
        int t = t0 + rr;
        float denom = smS[0][rr] + smS[1][rr] + smS[2][rr] + smS[3][rr];
        float sc = (t < melq) ? (1.0f / denom) : 0.f;
        size_t obase = ((size_t)(b * TDS + t)) * LL + cB;
#pragma unroll
        for (int lt = 0; lt < 4; ++lt)
            align_out[obase + lt * 128] = acc[lt][rg] * sc;
    }
}

// ---------------------------------------------------------------------------
// refine kernel: recompute flagged rows' 512 scores fully in f64, fix idx.
// ---------------------------------------------------------------------------
__global__ __launch_bounds__(256)
void refine_kernel(const float* __restrict__ q,
                   const float* __restrict__ k,
                   const int* __restrict__ text_lengths,
                   const int* __restrict__ mel_lengths,
                   const int* __restrict__ flags,
                   const int* __restrict__ flag_cnt,
                   int* __restrict__ idx_out) {
    __shared__ double qd[DD];
    __shared__ double invdiv[128];
    __shared__ double rbest[4];
    __shared__ int    ribest[4];
    const int tid = threadIdx.x;
    if (tid < 128)
        invdiv[tid] = 1.0 / pow(10000.0, (double)tid * (1.0 / 128.0));
    const int cnt = flag_cnt[0];
    for (int r = blockIdx.x; r < cnt; r += gridDim.x) {
        const int code = flags[r];
        const int b = code >> 11, t = code & 2047;
        const int tlen = text_lengths[b];
        const double ws = ((double)mel_lengths[b] * 0.25) / (double)text_lengths[b];
        __syncthreads();
        {
            const int d = tid, i = d >> 1;
            double ang = (double)t * invdiv[i];
            double sn, cs;
            sincos(ang, &sn, &cs);
            qd[d] = ((double)q[((size_t)b * TDS + t) * DD + d] + ((d & 1) ? cs : sn)) * 0.0625;
        }
        __syncthreads();
        double best = -1.0e300; int bi = 0x7fffffff;
        for (int p = 0; p < 2; ++p) {
            const int l = tid + p * 256;
            if (l < tlen) {
                const float* kr = k + ((size_t)b * LL + l) * DD;
                const double wl = ws * (double)l;
                double sacc = 0.0;
                for (int i = 0; i < 128; ++i) {
                    double ang = wl * invdiv[i];
                    double sn, cs;
                    sincos(ang, &sn, &cs);
                    sacc += ((double)kr[2 * i]     + sn) * qd[2 * i];
                    sacc += ((double)kr[2 * i + 1] + cs) * qd[2 * i + 1];
                }
                if (sacc > best || (sacc == best && l < bi)) { best = sacc; bi = l; }
            }
        }
        for (int off = 1; off <= 32; off <<= 1) {
            double ov = __shfl_xor(best, off, 64);
            int   oi = __shfl_xor(bi, off, 64);
            if (ov > best || (ov == best && oi < bi)) { best = ov; bi = oi; }
        }
        const int wv = tid >> 6;
        if ((tid & 63) == 0) { rbest[wv] = best; ribest[wv] = bi; }
        __syncthreads();
        if (tid == 0) {
            double bb = rbest[0]; int ii = ribest[0];
            for (int w = 1; w < 4; ++w)
                if (rbest[w] > bb || (rbest[w] == bb && ribest[w] < ii)) { bb = rbest[w]; ii = ribest[w]; }
            idx_out[b * TDS + t] = ii;
        }
    }
}

// ---------------------------------------------------------------------------
// compress kernel: out[b,c,t] = sum_d w[c,d] * v[b, idx[b,t], d] (0 if masked)
// ---------------------------------------------------------------------------
__global__ __launch_bounds__(256, 4)
void compress_kernel(const float* __restrict__ v,
                     const float* __restrict__ wc,
                     const int* __restrict__ idx_in,
                     const int* __restrict__ mel_lengths,
                     float* __restrict__ out) {
    __shared__ float Ws[256 * 68];
    __shared__ float Vs[16 * 132];
    __shared__ int   idxs[128];
    const int b   = blockIdx.y;
    const int t0  = blockIdx.x * 128;
    const int tid = threadIdx.x;
    const int melq = mel_lengths[b] >> 2;
    const float* vb = v + (size_t)b * LL * DD;

    if (tid < 128) {
        int t = t0 + tid;
        int ii = idx_in[b * TDS + t];
        idxs[tid] = (t >= melq) ? -1 : ii;
    }
#pragma unroll
    for (int r = 0; r < 16; ++r) {
        int f = tid + r * 256;
        int c = f >> 6;
        int u = f & 63;
        float4 wv = *(const float4*)(wc + (size_t)c * DD + u * 4);
        Ws[(u * 4 + 0) * 68 + c] = wv.x;
        Ws[(u * 4 + 1) * 68 + c] = wv.y;
        Ws[(u * 4 + 2) * 68 + c] = wv.z;
        Ws[(u * 4 + 3) * 68 + c] = wv.w;
    }

    const int tx = tid & 7;
    const int ty = tid >> 3;
    const int tv = tid >> 2;
    const int uv = tid & 3;
    float acc[8][4];
#pragma unroll
    for (int i = 0; i < 8; ++i)
#pragma unroll
        for (int j = 0; j < 4; ++j) acc[i][j] = 0.f;

    for (int ks = 0; ks < 16; ++ks) {
        const int d0 = ks * 16;
        __syncthreads();
#pragma unroll
        for (int p = 0; p < 2; ++p) {
            int t = tv + p * 64;
            int row = idxs[t];
            float4 vv = make_float4(0.f, 0.f, 0.f, 0.f);
            if (row >= 0) vv = *(const float4*)(vb + (size_t)row * DD + d0 + uv * 4);
            Vs[(uv * 4 + 0) * 132 + t] = vv.x;
            Vs[(uv * 4 + 1) * 132 + t] = vv.y;
            Vs[(uv * 4 + 2) * 132 + t] = vv.z;
            Vs[(uv * 4 + 3) * 132 + t] = vv.w;
        }
        __syncthreads();
#pragma unroll
        for (int kk = 0; kk < 16; ++kk) {
            const float* wrow = Ws + (size_t)(d0 + kk) * 68 + tx * 8;
            float4 a0 = *(const float4*)(wrow);
            float4 a1 = *(const float4*)(wrow + 4);
            float4 bb = *(const float4*)(Vs + kk * 132 + ty * 4);
            const float av[8] = {a0.x, a0.y, a0.z, a0.w, a1.x, a1.y, a1.z, a1.w};
            const float bv[4] = {bb.x, bb.y, bb.z, bb.w};
#pragma unroll
            for (int i = 0; i < 8; ++i)
#pragma unroll
                for (int j = 0; j < 4; ++j)
                    acc[i][j] = fmaf(av[i], bv[j], acc[i][j]);
        }
    }
#pragma unroll
    for (int ci = 0; ci < 8; ++ci) {
        int c = tx * 8 + ci;
        float4 o;
        o.x = acc[ci][0]; o.y = acc[ci][1]; o.z = acc[ci][2]; o.w = acc[ci][3];
        *(float4*)(out + ((size_t)(b * DC + c)) * TDS + t0 + ty * 4) = o;
    }
}

extern "C" void kernel_launch(void* const* d_in, const int* in_sizes, int n_in,
                              void* d_out, int out_size, void* d_ws, size_t ws_size,
                              hipStream_t stream) {
    const float* q    = (const float*)d_in[0];
    const float* k    = (const float*)d_in[1];
    const float* v    = (const float*)d_in[2];
    const float* wc   = (const float*)d_in[3];
    const int*   text = (const int*)d_in[4];
    const int*   mel  = (const int*)d_in[5];

    float* out   = (float*)d_out;
    float* align = out + (size_t)NB * DC * TDS;

    char*  wsb = (char*)d_ws;
    char*  KPS_HI = wsb;
    char*  KPS_LO = wsb + 8388608;
    float* PEQ = (float*)(wsb + 16777216);
    int*   IDX = (int*)(wsb + 16777216 + 2097152);
    int*   CNT = IDX + (size_t)NB * TDS;
    int*   FLG = CNT + 1;

    hipLaunchKernelGGL(init_cnt_kernel, dim3(1), dim3(64), 0, stream, CNT);
    hipLaunchKernelGGL(peq_kernel, dim3(TDS * DD / 256), dim3(256), 0, stream, PEQ);
    hipLaunchKernelGGL(pek_kernel, dim3(NB * LL * 32 / 256), dim3(256), 0, stream,
                       k, text, mel, KPS_HI, KPS_LO);
    hipLaunchKernelGGL(score_kernel, dim3(1024), dim3(512), 0, stream,
                       q, PEQ, KPS_HI, KPS_LO, text, mel, align, IDX, CNT, FLG);
    hipLaunchKernelGGL(refine_kernel, dim3(128), dim3(256), 0, stream,
                       q, k, text, mel, FLG, CNT, IDX);
    hipLaunchKernelGGL(compress_kernel, dim3(TDS / 128, NB), dim3(256), 0, stream,
                       v, wc, IDX, mel, out);
}

// Round 6
// 233.638 us; speedup vs baseline: 4.9016x; 1.0489x over previous
//
#include <hip/hip_runtime.h>
#include <math.h>

#define NB  32
#define TDS 2048
#define LL  512
#define DD  256
#define DC  64   // D/RATIO
#define GAP_THR 4e-4f

typedef __attribute__((ext_vector_type(8)))  short short8;
typedef __attribute__((ext_vector_type(16))) float f32x16;
typedef __attribute__((ext_vector_type(4)))  float f32x4;

__device__ __forceinline__ unsigned short f2bf(float x) {
    union { float f; unsigned u; } v; v.f = x;
    unsigned r = v.u + 0x7fffu + ((v.u >> 16) & 1u);
    return (unsigned short)(r >> 16);
}
__device__ __forceinline__ float bf2f(unsigned short h) {
    union { unsigned u; float f; } v; v.u = ((unsigned)h) << 16;
    return v.f;
}
__device__ __forceinline__ void gll16(const void* g, void* l) {
    __builtin_amdgcn_global_load_lds(
        (const __attribute__((address_space(1))) void*)g,
        (__attribute__((address_space(3))) void*)l, 16, 0, 0);
}
__device__ __forceinline__ int swz3(int x) { return (x & 7) ^ ((x >> 3) & 7); }

// ---------------------------------------------------------------------------
// ws layout (bytes):
//   [0, 8388608)            : KPS_HI  bf16 hi-plane of k+pe_k, swizzled image
//   [8388608, 16777216)     : KPS_LO  bf16 lo-plane
//   [16777216, 18874368)    : PEQ f32 (pe_q with w_s=1)
//   then NB*TDS ints IDX, 1 int CNT, NB*TDS ints FLAGS
// KPS image: per b per plane 262144 B = [ks 0..7][lt 0..3] tiles of 8192 B.
//   tile element (c 0..127, kk 0..31): byte = (c*64 + kk*2) ^ (swz3(c)<<4)
// ---------------------------------------------------------------------------

__global__ void peq_kernel(float* __restrict__ peq, int* __restrict__ cnt) {
    int idx = blockIdx.x * 256 + threadIdx.x;        // < TDS*DD
    if (idx == 0) cnt[0] = 0;
    int t = idx >> 8;
    int d = idx & 255;
    int i = d >> 1;
    double invdiv = exp((double)i * (-9.210340371976184 / 128.0));
    double ang = (double)t * invdiv;
    double s, c;
    sincos(ang, &s, &c);
    peq[idx] = (float)((d & 1) ? c : s);
}

// k + pe_k, split into bf16 hi/lo planes, written in the tiled+swizzled image.
__global__ __launch_bounds__(256)
void pek_kernel(const float* __restrict__ k,
                const int* __restrict__ text_lengths,
                const int* __restrict__ mel_lengths,
                char* __restrict__ hi_base,
                char* __restrict__ lo_base) {
    __shared__ double invdiv[128];
    const int tid = threadIdx.x;
    if (tid < 128) invdiv[tid] = exp((double)tid * (-9.210340371976184 / 128.0));
    __syncthreads();
    int f = blockIdx.x * 256 + tid;                  // < NB*512*32
    int b = f >> 14;
    int r = f & 16383;
    int ks = r >> 11;
    int rr = r & 2047;
    int lt = rr >> 9;
    int r2 = rr & 511;
    int c  = r2 >> 2;
    int ch = r2 & 3;
    int l  = lt * 128 + c;
    int kk = ks * 32 + ch * 8;
    const float* kr = k + ((size_t)(b * LL + l)) * DD + kk;
    float4 kv0 = *(const float4*)(kr);
    float4 kv1 = *(const float4*)(kr + 4);
    float kv[8] = {kv0.x, kv0.y, kv0.z, kv0.w, kv1.x, kv1.y, kv1.z, kv1.w};
    double wsd = ((double)mel_lengths[b] * 0.25) / (double)text_lengths[b];
    double base_ang = wsd * (double)l;
    unsigned short h[8], lo8[8];
#pragma unroll
    for (int jj = 0; jj < 4; ++jj) {
        int i = (kk >> 1) + jj;
        double ang = base_ang * invdiv[i];
        double n = rint(ang * 0.15915494309189535);
        double red = fma(n, -6.283185307179586, ang);   // |red| <= pi
        float sn, cs;
        sincosf((float)red, &sn, &cs);
        float e0 = kv[2 * jj] + sn;
        float e1 = kv[2 * jj + 1] + cs;
        h[2 * jj]       = f2bf(e0);
        h[2 * jj + 1]   = f2bf(e1);
        lo8[2 * jj]     = f2bf(e0 - bf2f(h[2 * jj]));
        lo8[2 * jj + 1] = f2bf(e1 - bf2f(h[2 * jj + 1]));
    }
    size_t off = (size_t)b * 262144 + (size_t)(ks * 4 + lt) * 8192
               + (size_t)((c * 64 + ch * 16) ^ (swz3(c) << 4));
    uint4 hv, lv;
    hv.x = h[0] | ((unsigned)h[1] << 16); hv.y = h[2] | ((unsigned)h[3] << 16);
    hv.z = h[4] | ((unsigned)h[5] << 16); hv.w = h[6] | ((unsigned)h[7] << 16);
    lv.x = lo8[0] | ((unsigned)lo8[1] << 16); lv.y = lo8[2] | ((unsigned)lo8[3] << 16);
    lv.z = lo8[4] | ((unsigned)lo8[5] << 16); lv.w = lo8[6] | ((unsigned)lo8[7] << 16);
    *(uint4*)(hi_base + off) = hv;
    *(uint4*)(lo_base + off) = lv;
}

// ---------------------------------------------------------------------------
// score kernel: 64 t-rows x 512 l-cols per block via split-bf16 MFMA 32x32x16.
// 8 waves: wm = wid>>2 (32-row half), wn = wid&3 (32-col slot per lt tile).
// Counted-vmcnt pipeline: 3-deep B buffers (16KB each), 2-deep A (8KB each),
// one raw barrier per phase, vmcnt never drained to 0 in steady state.
// ---------------------------------------------------------------------------
__global__ __launch_bounds__(512, 4)
void score_kernel(const float* __restrict__ q,
                  const float* __restrict__ peq,
                  const char* __restrict__ kps_hi,
                  const char* __restrict__ kps_lo,
                  const int* __restrict__ text_lengths,
                  const int* __restrict__ mel_lengths,
                  float* __restrict__ align_out,
                  int* __restrict__ idx_out,
                  int* __restrict__ flag_cnt,
                  int* __restrict__ flags) {
    __shared__ alignas(16) char smB[3 * 16384];   // per buf: [hi 8KB][lo 8KB]
    __shared__ alignas(16) char smA[2 * 8192];    // per buf: [hi 4KB][lo 4KB]
    __shared__ float smv1[4][64];
    __shared__ int   smi1[4][64];
    __shared__ float smv2[4][64];
    __shared__ float smS[4][64];
    __shared__ float smM[64];

    const int wgid = blockIdx.x;
    const int xcd = wgid & 7, loc = wgid >> 3;
    const int nid = xcd * 128 + loc;        // XCD-contiguous: 4 b's per XCD
    const int b = nid >> 5;
    const int t0 = (nid & 31) * 64;

    const int tid = threadIdx.x;
    const int wid = tid >> 6, lane = tid & 63;
    const int wm = wid >> 2, wn = wid & 3;
    const int c31 = lane & 31, hi5 = lane >> 5;
    const int tlen = text_lengths[b];
    const int melq = mel_lengths[b] >> 2;

    const char* khb = kps_hi + (size_t)b * 262144;
    const char* klb = kps_lo + (size_t)b * 262144;

    f32x16 acc[4];
#pragma unroll
    for (int lt = 0; lt < 4; ++lt)
#pragma unroll
        for (int rg = 0; rg < 16; ++rg) acc[lt][rg] = 0.f;

    // fragment read offsets (<=2-way bank conflict via XOR swizzle)
    const int rowA = wm * 32 + c31;
    const int cB   = wn * 32 + c31;
    int aoff[2], boff[2];
#pragma unroll
    for (int kh = 0; kh < 2; ++kh) {
        aoff[kh] = (rowA * 64 + kh * 32 + hi5 * 16) ^ (swz3(rowA) << 4);
        boff[kh] = (cB   * 64 + kh * 32 + hi5 * 16) ^ (swz3(cB)   << 4);
    }

    // A staging assignment: thread -> (row, 4 k-elems)
    const int sr  = tid >> 3;
    const int sk0 = (tid & 7) * 4;
    const float* qrow = q   + ((size_t)(b * TDS + t0 + sr)) * DD + sk0;
    const float* prow = peq + ((size_t)(t0 + sr)) * DD + sk0;
    const int awaddr = (sr * 64 + sk0 * 2) ^ (swz3(sr) << 4);

#define STAGEB(bbuf, ksv, ltv)                                                  \
    {                                                                           \
        const size_t toff = (size_t)(((ksv) * 4 + (ltv)) * 8192) + tid * 16;    \
        gll16(khb + toff, smB + (bbuf) * 16384 + tid * 16);                     \
        gll16(klb + toff, smB + (bbuf) * 16384 + 8192 + tid * 16);              \
    }
#define AWRITE(abufi)                                                           \
    {                                                                           \
        float a0 = (qv4.x + pv4.x) * 0.0625f, a1 = (qv4.y + pv4.y) * 0.0625f;   \
        float a2 = (qv4.z + pv4.z) * 0.0625f, a3 = (qv4.w + pv4.w) * 0.0625f;   \
        unsigned short h0 = f2bf(a0), h1 = f2bf(a1), h2 = f2bf(a2), h3 = f2bf(a3); \
        ushort4 hv = {h0, h1, h2, h3};                                          \
        ushort4 lv = {f2bf(a0 - bf2f(h0)), f2bf(a1 - bf2f(h1)),                 \
                      f2bf(a2 - bf2f(h2)), f2bf(a3 - bf2f(h3))};                \
        *(ushort4*)(smA + (abufi) * 8192 + awaddr) = hv;                        \
        *(ushort4*)(smA + (abufi) * 8192 + 4096 + awaddr) = lv;                 \
    }
#define MFMA_PHASE(LT)                                                          \
    {                                                                           \
        const char* bbase = smB + bp * 16384;                                   \
        short8 bh0 = *(const short8*)(bbase + boff[0]);                         \
        short8 bl0 = *(const short8*)(bbase + 8192 + boff[0]);                  \
        short8 bh1 = *(const short8*)(bbase + boff[1]);                         \
        short8 bl1 = *(const short8*)(bbase + 8192 + boff[1]);                  \
        asm volatile("s_waitcnt lgkmcnt(0)" ::: "memory");                      \
        __builtin_amdgcn_sched_barrier(0);                                      \
        __builtin_amdgcn_s_setprio(1);                                          \
        acc[LT] = __builtin_amdgcn_mfma_f32_32x32x16_bf16(ah0, bh0, acc[LT], 0, 0, 0); \
        acc[LT] = __builtin_amdgcn_mfma_f32_32x32x16_bf16(ah0, bl0, acc[LT], 0, 0, 0); \
        acc[LT] = __builtin_amdgcn_mfma_f32_32x32x16_bf16(al0, bh0, acc[LT], 0, 0, 0); \
        acc[LT] = __builtin_amdgcn_mfma_f32_32x32x16_bf16(ah1, bh1, acc[LT], 0, 0, 0); \
        acc[LT] = __builtin_amdgcn_mfma_f32_32x32x16_bf16(ah1, bl1, acc[LT], 0, 0, 0); \
        acc[LT] = __builtin_amdgcn_mfma_f32_32x32x16_bf16(al1, bh1, acc[LT], 0, 0, 0); \
        __builtin_amdgcn_s_setprio(0);                                          \
    }
#define ENDPHASE(NSTR)                                                          \
    asm volatile("s_waitcnt " NSTR " lgkmcnt(0)" ::: "memory");                 \
    __builtin_amdgcn_s_barrier();                                               \
    ++bp; if (bp == 3) bp = 0;

    // ---- prologue: A(ks0) -> abuf0; B phases 0,1 -> buf0,buf1 ----
    float4 qv4, pv4;
    qv4 = *(const float4*)(qrow);
    pv4 = *(const float4*)(prow);
    AWRITE(0)
    STAGEB(0, 0, 0)
    STAGEB(1, 0, 1)
    asm volatile("s_waitcnt vmcnt(2) lgkmcnt(0)" ::: "memory");
    __builtin_amdgcn_s_barrier();

    int bp = 0;
    short8 ah0, ah1, al0, al1;
    for (int ks = 0; ks < 7; ++ks) {
        const int ab = ks & 1;
        const char* abase = smA + ab * 8192;
        // ---- lt 0 ----
        {
            int bs = bp + 2; if (bs >= 3) bs -= 3;
            STAGEB(bs, ks, 2)
            ah0 = *(const short8*)(abase + aoff[0]);
            ah1 = *(const short8*)(abase + aoff[1]);
            al0 = *(const short8*)(abase + 4096 + aoff[0]);
            al1 = *(const short8*)(abase + 4096 + aoff[1]);
            MFMA_PHASE(0)
            ENDPHASE("vmcnt(2)")
        }
        // ---- lt 1 ----
        {
            int bs = bp + 2; if (bs >= 3) bs -= 3;
            STAGEB(bs, ks, 3)
            MFMA_PHASE(1)
            ENDPHASE("vmcnt(2)")
        }
        // ---- lt 2 : also issue A loads for ks+1 ----
        {
            int bs = bp + 2; if (bs >= 3) bs -= 3;
            STAGEB(bs, ks + 1, 0)
            qv4 = *(const float4*)(qrow + (ks + 1) * 32);
            pv4 = *(const float4*)(prow + (ks + 1) * 32);
            MFMA_PHASE(2)
            ENDPHASE("vmcnt(4)")
        }
        // ---- lt 3 : convert + ds_write A for ks+1 ----
        {
            int bs = bp + 2; if (bs >= 3) bs -= 3;
            STAGEB(bs, ks + 1, 1)
            MFMA_PHASE(3)
            AWRITE(ab ^ 1)
            ENDPHASE("vmcnt(2)")
        }
    }
    // ---- ks = 7 tail ----
    {
        const char* abase = smA + 8192;
        {
            int bs = bp + 2; if (bs >= 3) bs -= 3;
            STAGEB(bs, 7, 2)
            ah0 = *(const short8*)(abase + aoff[0]);
            ah1 = *(const short8*)(abase + aoff[1]);
            al0 = *(const short8*)(abase + 4096 + aoff[0]);
            al1 = *(const short8*)(abase + 4096 + aoff[1]);
            MFMA_PHASE(0)
            ENDPHASE("vmcnt(2)")
        }
        {
            int bs = bp + 2; if (bs >= 3) bs -= 3;
            STAGEB(bs, 7, 3)
            MFMA_PHASE(1)
            ENDPHASE("vmcnt(2)")
        }
        {
            MFMA_PHASE(2)
            ENDPHASE("vmcnt(0)")
        }
        {
            MFMA_PHASE(3)
            // last phase: no stage, no barrier needed before epilogue
        }
    }
#undef STAGEB
#undef AWRITE
#undef MFMA_PHASE
#undef ENDPHASE

    // ---- epilogue: mask, top-2, softmax, stores (32x32 C layout:
    //      col = lane&31 (within 32-col slot), row = (rg&3)+8*(rg>>2)+4*hi5) ----
    const float NEGINF = -__builtin_inff();
#pragma unroll
    for (int lt = 0; lt < 4; ++lt) {
        int col = lt * 128 + cB;
        if (col >= tlen) {
#pragma unroll
            for (int rg = 0; rg < 16; ++rg) acc[lt][rg] = NEGINF;
        }
    }
    float v1[16]; int i1[16]; float v2[16];
#pragma unroll
    for (int rg = 0; rg < 16; ++rg) {
        v1[rg] = acc[0][rg]; i1[rg] = cB; v2[rg] = NEGINF;
#pragma unroll
        for (int lt = 1; lt < 4; ++lt) {
            float v = acc[lt][rg]; int col = lt * 128 + cB;
            if (v > v1[rg]) { v2[rg] = v1[rg]; v1[rg] = v; i1[rg] = col; }
            else if (v > v2[rg]) v2[rg] = v;
        }
    }
#pragma unroll
    for (int off = 1; off <= 16; off <<= 1) {
#pragma unroll
        for (int rg = 0; rg < 16; ++rg) {
            float ov1 = __shfl_xor(v1[rg], off, 64);
            int   oi1 = __shfl_xor(i1[rg], off, 64);
            float ov2 = __shfl_xor(v2[rg], off, 64);
            if (ov1 > v1[rg]) { v2[rg] = fmaxf(v1[rg], ov2); v1[rg] = ov1; i1[rg] = oi1; }
            else if (ov1 < v1[rg]) { v2[rg] = fmaxf(v2[rg], ov1); }
            else { i1[rg] = min(i1[rg], oi1); v2[rg] = v1[rg]; }
        }
    }
    if (c31 == 0) {
#pragma unroll
        for (int rg = 0; rg < 16; ++rg) {
            int r64 = wm * 32 + (rg & 3) + 8 * (rg >> 2) + 4 * hi5;
            smv1[wn][r64] = v1[rg]; smi1[wn][r64] = i1[rg]; smv2[wn][r64] = v2[rg];
        }
    }
    __syncthreads();
    {
        const int r64 = wm * 32 + c31;
        float V1 = smv1[0][r64]; int I1 = smi1[0][r64]; float V2 = smv2[0][r64];
#pragma unroll
        for (int w = 1; w < 4; ++w) {
            float cv1 = smv1[w][r64]; int ci1 = smi1[w][r64]; float cv2 = smv2[w][r64];
            if (cv1 > V1) { V2 = fmaxf(V1, cv2); V1 = cv1; I1 = ci1; }
            else if (cv1 < V1) { V2 = fmaxf(V2, cv1); }
            else { V2 = V1; }
        }
        if (wn == 0 && hi5 == 0) {
            int t = t0 + r64;
            idx_out[b * TDS + t] = I1;
            if (t < melq && (V1 - V2) < GAP_THR) {
                int pos = atomicAdd(flag_cnt, 1);
                flags[pos] = (b << 11) | t;
            }
            smM[r64] = V1;
        }
    }
    __syncthreads();
    float ssum[16];
#pragma unroll
    for (int rg = 0; rg < 16; ++rg) {
        int rr = wm * 32 + (rg & 3) + 8 * (rg >> 2) + 4 * hi5;
        float M = smM[rr];
        float s = 0.f;
#pragma unroll
        for (int lt = 0; lt < 4; ++lt) {
            float p = __expf(acc[lt][rg] - M);
            acc[lt][rg] = p; s += p;
        }
        ssum[rg] = s;
    }
#pragma unroll
    for (int off = 1; off <= 16; off <<= 1)
#pragma unroll
        for (int rg = 0; rg < 16; ++rg) ssum[rg] += __shfl_xor(ssum[rg], off, 64);
    if (c31 == 0) {
#pragma unroll
        for (int rg = 0; rg < 16; ++rg) {
            int rr = wm * 32 + (rg & 3) + 8 * (rg >> 2) + 4 * hi5;
            smS[wn][rr] = ssum[rg];
        }
    }
    __syncthreads();
#pragma unroll
    for (int rg = 0; rg < 16; ++rg) {
        int rr = wm * 32 + (rg & 3) + 8 * (rg >> 2) + 4 * hi5;
        int t = t0 + rr;
        float denom = smS[0][rr] + smS[1][rr] + smS[2][rr] + smS[3][rr];
        float sc = (t < melq) ? (1.0f / denom) : 0.f;
        size_t obase = ((size_t)(b * TDS + t)) * LL + cB;
#pragma unroll
        for (int lt = 0; lt < 4; ++lt)
            __builtin_nontemporal_store(acc[lt][rg] * sc, align_out + obase + lt * 128);
    }
}

// ---------------------------------------------------------------------------
// refine kernel: recompute flagged rows' 512 scores fully in f64, fix idx.
// ---------------------------------------------------------------------------
__global__ __launch_bounds__(256)
void refine_kernel(const float* __restrict__ q,
                   const float* __restrict__ k,
                   const int* __restrict__ text_lengths,
                   const int* __restrict__ mel_lengths,
                   const int* __restrict__ flags,
                   const int* __restrict__ flag_cnt,
                   int* __restrict__ idx_out) {
    __shared__ double qd[DD];
    __shared__ double invdiv[128];
    __shared__ double rbest[4];
    __shared__ int    ribest[4];
    const int tid = threadIdx.x;
    if (tid < 128)
        invdiv[tid] = 1.0 / pow(10000.0, (double)tid * (1.0 / 128.0));
    const int cnt = flag_cnt[0];
    for (int r = blockIdx.x; r < cnt; r += gridDim.x) {
        const int code = flags[r];
        const int b = code >> 11, t = code & 2047;
        const int tlen = text_lengths[b];
        const double ws = ((double)mel_lengths[b] * 0.25) / (double)text_lengths[b];
        __syncthreads();
        {
            const int d = tid, i = d >> 1;
            double ang = (double)t * invdiv[i];
            double sn, cs;
            sincos(ang, &sn, &cs);
            qd[d] = ((double)q[((size_t)b * TDS + t) * DD + d] + ((d & 1) ? cs : sn)) * 0.0625;
        }
        __syncthreads();
        double best = -1.0e300; int bi = 0x7fffffff;
        for (int p = 0; p < 2; ++p) {
            const int l = tid + p * 256;
            if (l < tlen) {
                const float* kr = k + ((size_t)b * LL + l) * DD;
                const double wl = ws * (double)l;
                double sacc = 0.0;
                for (int i = 0; i < 128; ++i) {
                    double ang = wl * invdiv[i];
                    double sn, cs;
                    sincos(ang, &sn, &cs);
                    sacc += ((double)kr[2 * i]     + sn) * qd[2 * i];
                    sacc += ((double)kr[2 * i + 1] + cs) * qd[2 * i + 1];
                }
                if (sacc > best || (sacc == best && l < bi)) { best = sacc; bi = l; }
            }
        }
        for (int off = 1; off <= 32; off <<= 1) {
            double ov = __shfl_xor(best, off, 64);
            int   oi = __shfl_xor(bi, off, 64);
            if (ov > best || (ov == best && oi < bi)) { best = ov; bi = oi; }
        }
        const int wv = tid >> 6;
        if ((tid & 63) == 0) { rbest[wv] = best; ribest[wv] = bi; }
        __syncthreads();
        if (tid == 0) {
            double bb = rbest[0]; int ii = ribest[0];
            for (int w = 1; w < 4; ++w)
                if (rbest[w] > bb || (rbest[w] == bb && ribest[w] < ii)) { bb = rbest[w]; ii = ribest[w]; }
            idx_out[b * TDS + t] = ii;
        }
    }
}

// ---------------------------------------------------------------------------
// compress kernel: out[b,c,t] = sum_d w[c,d] * v[b, idx[b,t], d] (0 if masked)
// ---------------------------------------------------------------------------
__global__ __launch_bounds__(256, 4)
void compress_kernel(const float* __restrict__ v,
                     const float* __restrict__ wc,
                     const int* __restrict__ idx_in,
                     const int* __restrict__ mel_lengths,
                     float* __restrict__ out) {
    __shared__ float Ws[256 * 68];
    __shared__ float Vs[16 * 132];
    __shared__ int   idxs[128];
    const int b   = blockIdx.y;
    const int t0  = blockIdx.x * 128;
    const int tid = threadIdx.x;
    const int melq = mel_lengths[b] >> 2;
    const float* vb = v + (size_t)b * LL * DD;

    if (tid < 128) {
        int t = t0 + tid;
        int ii = idx_in[b * TDS + t];
        idxs[tid] = (t >= melq) ? -1 : ii;
    }
#pragma unroll
    for (int r = 0; r < 16; ++r) {
        int f = tid + r * 256;
        int c = f >> 6;
        int u = f & 63;
        float4 wv = *(const float4*)(wc + (size_t)c * DD + u * 4);
        Ws[(u * 4 + 0) * 68 + c] = wv.x;
        Ws[(u * 4 + 1) * 68 + c] = wv.y;
        Ws[(u * 4 + 2) * 68 + c] = wv.z;
        Ws[(u * 4 + 3) * 68 + c] = wv.w;
    }

    const int tx = tid & 7;
    const int ty = tid >> 3;
    const int tv = tid >> 2;
    const int uv = tid & 3;
    float acc[8][4];
#pragma unroll
    for (int i = 0; i < 8; ++i)
#pragma unroll
        for (int j = 0; j < 4; ++j) acc[i][j] = 0.f;

    for (int ks = 0; ks < 16; ++ks) {
        const int d0 = ks * 16;
        __syncthreads();
#pragma unroll
        for (int p = 0; p < 2; ++p) {
            int t = tv + p * 64;
            int row = idxs[t];
            float4 vv = make_float4(0.f, 0.f, 0.f, 0.f);
            if (row >= 0) vv = *(const float4*)(vb + (size_t)row * DD + d0 + uv * 4);
            Vs[(uv * 4 + 0) * 132 + t] = vv.x;
            Vs[(uv * 4 + 1) * 132 + t] = vv.y;
            Vs[(uv * 4 + 2) * 132 + t] = vv.z;
            Vs[(uv * 4 + 3) * 132 + t] = vv.w;
        }
        __syncthreads();
#pragma unroll
        for (int kk = 0; kk < 16; ++kk) {
            const float* wrow = Ws + (size_t)(d0 + kk) * 68 + tx * 8;
            float4 a0 = *(const float4*)(wrow);
            float4 a1 = *(const float4*)(wrow + 4);
            float4 bb = *(const float4*)(Vs + kk * 132 + ty * 4);
            const float av[8] = {a0.x, a0.y, a0.z, a0.w, a1.x, a1.y, a1.z, a1.w};
            const float bv[4] = {bb.x, bb.y, bb.z, bb.w};
#pragma unroll
            for (int i = 0; i < 8; ++i)
#pragma unroll
                for (int j = 0; j < 4; ++j)
                    acc[i][j] = fmaf(av[i], bv[j], acc[i][j]);
        }
    }
#pragma unroll
    for (int ci = 0; ci < 8; ++ci) {
        int c = tx * 8 + ci;
        f32x4 o = {acc[ci][0], acc[ci][1], acc[ci][2], acc[ci][3]};
        __builtin_nontemporal_store(o, (f32x4*)(out + ((size_t)(b * DC + c)) * TDS + t0 + ty * 4));
    }
}

extern "C" void kernel_launch(void* const* d_in, const int* in_sizes, int n_in,
                              void* d_out, int out_size, void* d_ws, size_t ws_size,
                              hipStream_t stream) {
    const float* q    = (const float*)d_in[0];
    const float* k    = (const float*)d_in[1];
    const float* v    = (const float*)d_in[2];
    const float* wc   = (const float*)d_in[3];
    const int*   text = (const int*)d_in[4];
    const int*   mel  = (const int*)d_in[5];

    float* out   = (float*)d_out;
    float* align = out + (size_t)NB * DC * TDS;

    char*  wsb = (char*)d_ws;
    char*  KPS_HI = wsb;
    char*  KPS_LO = wsb + 8388608;
    float* PEQ = (float*)(wsb + 16777216);
    int*   IDX = (int*)(wsb + 16777216 + 2097152);
    int*   CNT = IDX + (size_t)NB * TDS;
    int*   FLG = CNT + 1;

    hipLaunchKernelGGL(peq_kernel, dim3(TDS * DD / 256), dim3(256), 0, stream, PEQ, CNT);
    hipLaunchKernelGGL(pek_kernel, dim3(NB * LL * 32 / 256), dim3(256), 0, stream,
                       k, text, mel, KPS_HI, KPS_LO);
    hipLaunchKernelGGL(score_kernel, dim3(1024), dim3(512), 0, stream,
                       q, PEQ, KPS_HI, KPS_LO, text, mel, align, IDX, CNT, FLG);
    hipLaunchKernelGGL(refine_kernel, dim3(128), dim3(256), 0, stream,
                       q, k, text, mel, FLG, CNT, IDX);
    hipLaunchKernelGGL(compress_kernel, dim3(TDS / 128, NB), dim3(256), 0, stream,
                       v, wc, IDX, mel, out);
}

// Round 7
// 232.366 us; speedup vs baseline: 4.9285x; 1.0055x over previous
//
#include <hip/hip_runtime.h>
#include <math.h>

#define NB  32
#define TDS 2048
#define LL  512
#define DD  256
#define DC  64   // D/RATIO
#define GAP_THR 4e-4f

typedef __attribute__((ext_vector_type(8)))  short short8;
typedef __attribute__((ext_vector_type(16))) float f32x16;
typedef __attribute__((ext_vector_type(4)))  float f32x4;

__device__ __forceinline__ unsigned short f2bf(float x) {
    union { float f; unsigned u; } v; v.f = x;
    unsigned r = v.u + 0x7fffu + ((v.u >> 16) & 1u);
    return (unsigned short)(r >> 16);
}
__device__ __forceinline__ float bf2f(unsigned short h) {
    union { unsigned u; float f; } v; v.u = ((unsigned)h) << 16;
    return v.f;
}
__device__ __forceinline__ void gll16(const void* g, void* l) {
    __builtin_amdgcn_global_load_lds(
        (const __attribute__((address_space(1))) void*)g,
        (__attribute__((address_space(3))) void*)l, 16, 0, 0);
}
__device__ __forceinline__ int swz3(int x) { return (x & 7) ^ ((x >> 3) & 7); }

// ---------------------------------------------------------------------------
// ws layout (bytes):
//   [0, 8388608)            : KPS_HI  bf16 hi-plane of k+pe_k, swizzled image
//   [8388608, 16777216)     : KPS_LO  bf16 lo-plane
//   [16777216, 18874368)    : PEQ f32 (pe_q with w_s=1)
//   then NB*TDS ints IDX, 1 int CNT, NB*TDS ints FLAGS
// KPS image: per b per plane 262144 B = 32 tiles (ks*4+lt) of 8192 B.
//   tile element (c 0..127, kk 0..31): byte = (c*64 + kk*2) ^ (swz3(c)<<4)
// ---------------------------------------------------------------------------

__global__ void peq_kernel(float* __restrict__ peq, int* __restrict__ cnt) {
    int idx = blockIdx.x * 256 + threadIdx.x;        // < TDS*DD
    if (idx == 0) cnt[0] = 0;
    int t = idx >> 8;
    int d = idx & 255;
    int i = d >> 1;
    double invdiv = exp((double)i * (-9.210340371976184 / 128.0));
    double ang = (double)t * invdiv;
    double s, c;
    sincos(ang, &s, &c);
    peq[idx] = (float)((d & 1) ? c : s);
}

// k + pe_k, split into bf16 hi/lo planes, written in the tiled+swizzled image.
__global__ __launch_bounds__(256)
void pek_kernel(const float* __restrict__ k,
                const int* __restrict__ text_lengths,
                const int* __restrict__ mel_lengths,
                char* __restrict__ hi_base,
                char* __restrict__ lo_base) {
    __shared__ double invdiv[128];
    const int tid = threadIdx.x;
    if (tid < 128) invdiv[tid] = exp((double)tid * (-9.210340371976184 / 128.0));
    __syncthreads();
    int f = blockIdx.x * 256 + tid;                  // < NB*512*32
    int b = f >> 14;
    int r = f & 16383;
    int ks = r >> 11;
    int rr = r & 2047;
    int lt = rr >> 9;
    int r2 = rr & 511;
    int c  = r2 >> 2;
    int ch = r2 & 3;
    int l  = lt * 128 + c;
    int kk = ks * 32 + ch * 8;
    const float* kr = k + ((size_t)(b * LL + l)) * DD + kk;
    float4 kv0 = *(const float4*)(kr);
    float4 kv1 = *(const float4*)(kr + 4);
    float kv[8] = {kv0.x, kv0.y, kv0.z, kv0.w, kv1.x, kv1.y, kv1.z, kv1.w};
    double wsd = ((double)mel_lengths[b] * 0.25) / (double)text_lengths[b];
    double base_ang = wsd * (double)l;
    unsigned short h[8], lo8[8];
#pragma unroll
    for (int jj = 0; jj < 4; ++jj) {
        int i = (kk >> 1) + jj;
        double ang = base_ang * invdiv[i];
        double n = rint(ang * 0.15915494309189535);
        double red = fma(n, -6.283185307179586, ang);   // |red| <= pi
        float sn, cs;
        sincosf((float)red, &sn, &cs);
        float e0 = kv[2 * jj] + sn;
        float e1 = kv[2 * jj + 1] + cs;
        h[2 * jj]       = f2bf(e0);
        h[2 * jj + 1]   = f2bf(e1);
        lo8[2 * jj]     = f2bf(e0 - bf2f(h[2 * jj]));
        lo8[2 * jj + 1] = f2bf(e1 - bf2f(h[2 * jj + 1]));
    }
    size_t off = (size_t)b * 262144 + (size_t)(ks * 4 + lt) * 8192
               + (size_t)((c * 64 + ch * 16) ^ (swz3(c) << 4));
    uint4 hv, lv;
    hv.x = h[0] | ((unsigned)h[1] << 16); hv.y = h[2] | ((unsigned)h[3] << 16);
    hv.z = h[4] | ((unsigned)h[5] << 16); hv.w = h[6] | ((unsigned)h[7] << 16);
    lv.x = lo8[0] | ((unsigned)lo8[1] << 16); lv.y = lo8[2] | ((unsigned)lo8[3] << 16);
    lv.z = lo8[4] | ((unsigned)lo8[5] << 16); lv.w = lo8[6] | ((unsigned)lo8[7] << 16);
    *(uint4*)(hi_base + off) = hv;
    *(uint4*)(lo_base + off) = lv;
}

// ---------------------------------------------------------------------------
// score kernel: 32 t-rows x 512 l-cols per block, 256 threads = 4 waves.
// Wave wn owns 32x32 col-slot wn within each of the 4 lt 128-col tiles.
// LDS exactly 40KB -> 4 blocks/CU (4 independent barrier groups).
// Simple double-buffered loop, one __syncthreads per phase (32 phases).
// ---------------------------------------------------------------------------
__global__ __launch_bounds__(256, 4)
void score_kernel(const float* __restrict__ q,
                  const float* __restrict__ peq,
                  const char* __restrict__ kps_hi,
                  const char* __restrict__ kps_lo,
                  const int* __restrict__ text_lengths,
                  const int* __restrict__ mel_lengths,
                  float* __restrict__ align_out,
                  int* __restrict__ idx_out,
                  int* __restrict__ flag_cnt,
                  int* __restrict__ flags) {
    __shared__ alignas(16) char smB[2 * 16384];   // per buf: [hi 8KB][lo 8KB]
    __shared__ alignas(16) char smA[2 * 4096];    // per buf: [hi 2KB][lo 2KB]

    // epilogue scratch aliased into smA (used only after the main loop)
    struct Epi {
        float v1[4][32]; int i1[4][32]; float v2[4][32];
        float S[4][32];  float M[32];
    };
    Epi* ep = (Epi*)smA;

    const int wgid = blockIdx.x;                 // 2048 blocks, 2048%8==0
    const int xcd = wgid & 7, loc = wgid >> 3;
    const int nid = xcd * 256 + loc;             // XCD-contiguous: 4 b's/XCD
    const int b  = nid >> 6;
    const int t0 = (nid & 63) << 5;              // 32-row tile

    const int tid = threadIdx.x;
    const int wn = tid >> 6, lane = tid & 63;
    const int c31 = lane & 31, hi5 = lane >> 5;
    const int tlen = text_lengths[b];
    const int melq = mel_lengths[b] >> 2;

    const char* khb = kps_hi + (size_t)b * 262144;
    const char* klb = kps_lo + (size_t)b * 262144;

    f32x16 acc[4];
#pragma unroll
    for (int lt = 0; lt < 4; ++lt)
#pragma unroll
        for (int rg = 0; rg < 16; ++rg) acc[lt][rg] = 0.f;

    // fragment read offsets
    const int cB = wn * 32 + c31;                // col within 128-tile
    int aoff[2], boff[2];
#pragma unroll
    for (int kh = 0; kh < 2; ++kh) {
        aoff[kh] = (c31 * 64 + kh * 32 + hi5 * 16) ^ (swz3(c31) << 4);
        boff[kh] = (cB  * 64 + kh * 32 + hi5 * 16) ^ (swz3(cB)  << 4);
    }

    // A staging: thread -> (row sr 0..31, 4 k-elems at sk0)
    const int sr  = tid >> 3;
    const int sk0 = (tid & 7) * 4;
    const float* qrow = q   + ((size_t)(b * TDS + t0 + sr)) * DD + sk0;
    const float* prow = peq + ((size_t)(t0 + sr)) * DD + sk0;
    const int awaddr = (sr * 64 + sk0 * 2) ^ (swz3(sr) << 4);

#define STAGEB(dbuf, tidx)                                                      \
    {                                                                           \
        const size_t toff = (size_t)(tidx) * 8192 + tid * 16;                   \
        char* dh = smB + (dbuf) * 16384 + tid * 16;                             \
        char* dl = dh + 8192;                                                   \
        gll16(khb + toff, dh); gll16(khb + toff + 4096, dh + 4096);             \
        gll16(klb + toff, dl); gll16(klb + toff + 4096, dl + 4096);             \
    }
#define AWRITE(abufi)                                                           \
    {                                                                           \
        float a0 = (qv4.x + pv4.x) * 0.0625f, a1 = (qv4.y + pv4.y) * 0.0625f;   \
        float a2 = (qv4.z + pv4.z) * 0.0625f, a3 = (qv4.w + pv4.w) * 0.0625f;   \
        unsigned short h0 = f2bf(a0), h1 = f2bf(a1), h2 = f2bf(a2), h3 = f2bf(a3); \
        ushort4 hv = {h0, h1, h2, h3};                                          \
        ushort4 lv = {f2bf(a0 - bf2f(h0)), f2bf(a1 - bf2f(h1)),                 \
                      f2bf(a2 - bf2f(h2)), f2bf(a3 - bf2f(h3))};                \
        *(ushort4*)(smA + (abufi) * 4096 + awaddr) = hv;                        \
        *(ushort4*)(smA + (abufi) * 4096 + 2048 + awaddr) = lv;                 \
    }
#define MFMA6(LT, BUF)                                                          \
    {                                                                           \
        const char* bb = smB + (BUF) * 16384;                                   \
        short8 bh0 = *(const short8*)(bb + boff[0]);                            \
        short8 bl0 = *(const short8*)(bb + 8192 + boff[0]);                     \
        short8 bh1 = *(const short8*)(bb + boff[1]);                            \
        short8 bl1 = *(const short8*)(bb + 8192 + boff[1]);                     \
        acc[LT] = __builtin_amdgcn_mfma_f32_32x32x16_bf16(ah0, bh0, acc[LT], 0, 0, 0); \
        acc[LT] = __builtin_amdgcn_mfma_f32_32x32x16_bf16(ah0, bl0, acc[LT], 0, 0, 0); \
        acc[LT] = __builtin_amdgcn_mfma_f32_32x32x16_bf16(al0, bh0, acc[LT], 0, 0, 0); \
        acc[LT] = __builtin_amdgcn_mfma_f32_32x32x16_bf16(ah1, bh1, acc[LT], 0, 0, 0); \
        acc[LT] = __builtin_amdgcn_mfma_f32_32x32x16_bf16(ah1, bl1, acc[LT], 0, 0, 0); \
        acc[LT] = __builtin_amdgcn_mfma_f32_32x32x16_bf16(al1, bh1, acc[LT], 0, 0, 0); \
    }

    // ---- prologue: A(ks0) -> abuf0; B tile0 -> buf0 ----
    float4 qv4 = *(const float4*)(qrow);
    float4 pv4 = *(const float4*)(prow);
    AWRITE(0)
    STAGEB(0, 0)
    __syncthreads();

    for (int ks = 0; ks < 8; ++ks) {
        const char* abase = smA + (ks & 1) * 4096;
        short8 ah0 = *(const short8*)(abase + aoff[0]);
        short8 ah1 = *(const short8*)(abase + aoff[1]);
        short8 al0 = *(const short8*)(abase + 2048 + aoff[0]);
        short8 al1 = *(const short8*)(abase + 2048 + aoff[1]);
        const int p0 = ks * 4;
        // lt 0 (reads buf0, stages buf1)
        STAGEB(1, p0 + 1)
        MFMA6(0, 0)
        __syncthreads();
        // lt 1 (reads buf1, stages buf0); prefetch next A rows
        STAGEB(0, p0 + 2)
        if (ks < 7) {
            qv4 = *(const float4*)(qrow + (ks + 1) * 32);
            pv4 = *(const float4*)(prow + (ks + 1) * 32);
        }
        MFMA6(1, 1)
        __syncthreads();
        // lt 2 (reads buf0, stages buf1)
        STAGEB(1, p0 + 3)
        MFMA6(2, 0)
        __syncthreads();
        // lt 3 (reads buf1, stages buf0 with next ks lt0); write next A
        if (ks < 7) STAGEB(0, p0 + 4)
        MFMA6(3, 1)
        if (ks < 7) AWRITE((ks + 1) & 1)
        __syncthreads();
    }
#undef STAGEB
#undef AWRITE
#undef MFMA6

    // ---- epilogue: mask, top-2, softmax, stores (32x32 C layout:
    //      col = c31 within slot, row = (rg&3)+8*(rg>>2)+4*hi5) ----
    const float NEGINF = -__builtin_inff();
#pragma unroll
    for (int lt = 0; lt < 4; ++lt) {
        int col = lt * 128 + cB;
        if (col >= tlen) {
#pragma unroll
            for (int rg = 0; rg < 16; ++rg) acc[lt][rg] = NEGINF;
        }
    }
    float v1[16]; int i1[16]; float v2[16];
#pragma unroll
    for (int rg = 0; rg < 16; ++rg) {
        v1[rg] = acc[0][rg]; i1[rg] = cB; v2[rg] = NEGINF;
#pragma unroll
        for (int lt = 1; lt < 4; ++lt) {
            float v = acc[lt][rg]; int col = lt * 128 + cB;
            if (v > v1[rg]) { v2[rg] = v1[rg]; v1[rg] = v; i1[rg] = col; }
            else if (v > v2[rg]) v2[rg] = v;
        }
    }
#pragma unroll
    for (int off = 1; off <= 16; off <<= 1) {
#pragma unroll
        for (int rg = 0; rg < 16; ++rg) {
            float ov1 = __shfl_xor(v1[rg], off, 64);
            int   oi1 = __shfl_xor(i1[rg], off, 64);
            float ov2 = __shfl_xor(v2[rg], off, 64);
            if (ov1 > v1[rg]) { v2[rg] = fmaxf(v1[rg], ov2); v1[rg] = ov1; i1[rg] = oi1; }
            else if (ov1 < v1[rg]) { v2[rg] = fmaxf(v2[rg], ov1); }
            else { i1[rg] = min(i1[rg], oi1); v2[rg] = v1[rg]; }
        }
    }
    if (c31 == 0) {
#pragma unroll
        for (int rg = 0; rg < 16; ++rg) {
            int r32 = (rg & 3) + 8 * (rg >> 2) + 4 * hi5;
            ep->v1[wn][r32] = v1[rg]; ep->i1[wn][r32] = i1[rg]; ep->v2[wn][r32] = v2[rg];
        }
    }
    __syncthreads();
    {
        const int r32 = c31;
        float V1 = ep->v1[0][r32]; int I1 = ep->i1[0][r32]; float V2 = ep->v2[0][r32];
#pragma unroll
        for (int w = 1; w < 4; ++w) {
            float cv1 = ep->v1[w][r32]; int ci1 = ep->i1[w][r32]; float cv2 = ep->v2[w][r32];
            if (cv1 > V1) { V2 = fmaxf(V1, cv2); V1 = cv1; I1 = ci1; }
            else if (cv1 < V1) { V2 = fmaxf(V2, cv1); }
            else { V2 = V1; }
        }
        if (wn == 0 && hi5 == 0) {
            int t = t0 + r32;
            idx_out[b * TDS + t] = I1;
            if (t < melq && (V1 - V2) < GAP_THR) {
                int pos = atomicAdd(flag_cnt, 1);
                flags[pos] = (b << 11) | t;
            }
            ep->M[r32] = V1;
        }
    }
    __syncthreads();
    float ssum[16];
#pragma unroll
    for (int rg = 0; rg < 16; ++rg) {
        int r32 = (rg & 3) + 8 * (rg >> 2) + 4 * hi5;
        float M = ep->M[r32];
        float s = 0.f;
#pragma unroll
        for (int lt = 0; lt < 4; ++lt) {
            float p = __expf(acc[lt][rg] - M);
            acc[lt][rg] = p; s += p;
        }
        ssum[rg] = s;
    }
#pragma unroll
    for (int off = 1; off <= 16; off <<= 1)
#pragma unroll
        for (int rg = 0; rg < 16; ++rg) ssum[rg] += __shfl_xor(ssum[rg], off, 64);
    if (c31 == 0) {
#pragma unroll
        for (int rg = 0; rg < 16; ++rg) {
            int r32 = (rg & 3) + 8 * (rg >> 2) + 4 * hi5;
            ep->S[wn][r32] = ssum[rg];
        }
    }
    __syncthreads();
#pragma unroll
    for (int rg = 0; rg < 16; ++rg) {
        int r32 = (rg & 3) + 8 * (rg >> 2) + 4 * hi5;
        int t = t0 + r32;
        float denom = ep->S[0][r32] + ep->S[1][r32] + ep->S[2][r32] + ep->S[3][r32];
        float sc = (t < melq) ? (1.0f / denom) : 0.f;
        size_t obase = ((size_t)(b * TDS + t)) * LL + cB;
#pragma unroll
        for (int lt = 0; lt < 4; ++lt)
            __builtin_nontemporal_store(acc[lt][rg] * sc, align_out + obase + lt * 128);
    }
}

// ---------------------------------------------------------------------------
// refine kernel: recompute flagged rows' 512 scores fully in f64, fix idx.
// ---------------------------------------------------------------------------
__global__ __launch_bounds__(256)
void refine_kernel(const float* __restrict__ q,
                   const float* __restrict__ k,
                   const int* __restrict__ text_lengths,
                   const int* __restrict__ mel_lengths,
                   const int* __restrict__ flags,
                   const int* __restrict__ flag_cnt,
                   int* __restrict__ idx_out) {
    __shared__ double qd[DD];
    __shared__ double invdiv[128];
    __shared__ double rbest[4];
    __shared__ int    ribest[4];
    const int tid = threadIdx.x;
    if (tid < 128)
        invdiv[tid] = 1.0 / pow(10000.0, (double)tid * (1.0 / 128.0));
    const int cnt = flag_cnt[0];
    for (int r = blockIdx.x; r < cnt; r += gridDim.x) {
        const int code = flags[r];
        const int b = code >> 11, t = code & 2047;
        const int tlen = text_lengths[b];
        const double ws = ((double)mel_lengths[b] * 0.25) / (double)text_lengths[b];
        __syncthreads();
        {
            const int d = tid, i = d >> 1;
            double ang = (double)t * invdiv[i];
            double sn, cs;
            sincos(ang, &sn, &cs);
            qd[d] = ((double)q[((size_t)b * TDS + t) * DD + d] + ((d & 1) ? cs : sn)) * 0.0625;
        }
        __syncthreads();
        double best = -1.0e300; int bi = 0x7fffffff;
        for (int p = 0; p < 2; ++p) {
            const int l = tid + p * 256;
            if (l < tlen) {
                const float* kr = k + ((size_t)b * LL + l) * DD;
                const double wl = ws * (double)l;
                double sacc = 0.0;
                for (int i = 0; i < 128; ++i) {
                    double ang = wl * invdiv[i];
                    double sn, cs;
                    sincos(ang, &sn, &cs);
                    sacc += ((double)kr[2 * i]     + sn) * qd[2 * i];
                    sacc += ((double)kr[2 * i + 1] + cs) * qd[2 * i + 1];
                }
                if (sacc > best || (sacc == best && l < bi)) { best = sacc; bi = l; }
            }
        }
        for (int off = 1; off <= 32; off <<= 1) {
            double ov = __shfl_xor(best, off, 64);
            int   oi = __shfl_xor(bi, off, 64);
            if (ov > best || (ov == best && oi < bi)) { best = ov; bi = oi; }
        }
        const int wv = tid >> 6;
        if ((tid & 63) == 0) { rbest[wv] = best; ribest[wv] = bi; }
        __syncthreads();
        if (tid == 0) {
            double bb = rbest[0]; int ii = ribest[0];
            for (int w = 1; w < 4; ++w)
                if (rbest[w] > bb || (rbest[w] == bb && ribest[w] < ii)) { bb = rbest[w]; ii = ribest[w]; }
            idx_out[b * TDS + t] = ii;
        }
    }
}

// ---------------------------------------------------------------------------
// compress kernel: out[b,c,t] = sum_d w[c,d] * v[b, idx[b,t], d] (0 if masked)
// ---------------------------------------------------------------------------
__global__ __launch_bounds__(256, 4)
void compress_kernel(const float* __restrict__ v,
                     const float* __restrict__ wc,
                     const int* __restrict__ idx_in,
                     const int* __restrict__ mel_lengths,
                     float* __restrict__ out) {
    __shared__ float Ws[256 * 68];
    __shared__ float Vs[16 * 132];
    __shared__ int   idxs[128];
    const int b   = blockIdx.y;
    const int t0  = blockIdx.x * 128;
    const int tid = threadIdx.x;
    const int melq = mel_lengths[b] >> 2;
    const float* vb = v + (size_t)b * LL * DD;

    if (tid < 128) {
        int t = t0 + tid;
        int ii = idx_in[b * TDS + t];
        idxs[tid] = (t >= melq) ? -1 : ii;
    }
#pragma unroll
    for (int r = 0; r < 16; ++r) {
        int f = tid + r * 256;
        int c = f >> 6;
        int u = f & 63;
        float4 wv = *(const float4*)(wc + (size_t)c * DD + u * 4);
        Ws[(u * 4 + 0) * 68 + c] = wv.x;
        Ws[(u * 4 + 1) * 68 + c] = wv.y;
        Ws[(u * 4 + 2) * 68 + c] = wv.z;
        Ws[(u * 4 + 3) * 68 + c] = wv.w;
    }

    const int tx = tid & 7;
    const int ty = tid >> 3;
    const int tv = tid >> 2;
    const int uv = tid & 3;
    float acc[8][4];
#pragma unroll
    for (int i = 0; i < 8; ++i)
#pragma unroll
        for (int j = 0; j < 4; ++j) acc[i][j] = 0.f;

    for (int ks = 0; ks < 16; ++ks) {
        const int d0 = ks * 16;
        __syncthreads();
#pragma unroll
        for (int p = 0; p < 2; ++p) {
            int t = tv + p * 64;
            int row = idxs[t];
            float4 vv = make_float4(0.f, 0.f, 0.f, 0.f);
            if (row >= 0) vv = *(const float4*)(vb + (size_t)row * DD + d0 + uv * 4);
            Vs[(uv * 4 + 0) * 132 + t] = vv.x;
            Vs[(uv * 4 + 1) * 132 + t] = vv.y;
            Vs[(uv * 4 + 2) * 132 + t] = vv.z;
            Vs[(uv * 4 + 3) * 132 + t] = vv.w;
        }
        __syncthreads();
#pragma unroll
        for (int kk = 0; kk < 16; ++kk) {
            const float* wrow = Ws + (size_t)(d0 + kk) * 68 + tx * 8;
            float4 a0 = *(const float4*)(wrow);
            float4 a1 = *(const float4*)(wrow + 4);
            float4 bb = *(const float4*)(Vs + kk * 132 + ty * 4);
            const float av[8] = {a0.x, a0.y, a0.z, a0.w, a1.x, a1.y, a1.z, a1.w};
            const float bv[4] = {bb.x, bb.y, bb.z, bb.w};
#pragma unroll
            for (int i = 0; i < 8; ++i)
#pragma unroll
                for (int j = 0; j < 4; ++j)
                    acc[i][j] = fmaf(av[i], bv[j], acc[i][j]);
        }
    }
#pragma unroll
    for (int ci = 0; ci < 8; ++ci) {
        int c = tx * 8 + ci;
        f32x4 o = {acc[ci][0], acc[ci][1], acc[ci][2], acc[ci][3]};
        __builtin_nontemporal_store(o, (f32x4*)(out + ((size_t)(b * DC + c)) * TDS + t0 + ty * 4));
    }
}

extern "C" void kernel_launch(void* const* d_in, const int* in_sizes, int n_in,
                              void* d_out, int out_size, void* d_ws, size_t ws_size,
                              hipStream_t stream) {
    const float* q    = (const float*)d_in[0];
    const float* k    = (const float*)d_in[1];
    const float* v    = (const float*)d_in[2];
    const float* wc   = (const float*)d_in[3];
    const int*   text = (const int*)d_in[4];
    const int*   mel  = (const int*)d_in[5];

    float* out   = (float*)d_out;
    float* align = out + (size_t)NB * DC * TDS;

    char*  wsb = (char*)d_ws;
    char*  KPS_HI = wsb;
    char*  KPS_LO = wsb + 8388608;
    float* PEQ = (float*)(wsb + 16777216);
    int*   IDX = (int*)(wsb + 16777216 + 2097152);
    int*   CNT = IDX + (size_t)NB * TDS;
    int*   FLG = CNT + 1;

    hipLaunchKernelGGL(peq_kernel, dim3(TDS * DD / 256), dim3(256), 0, stream, PEQ, CNT);
    hipLaunchKernelGGL(pek_kernel, dim3(NB * LL * 32 / 256), dim3(256), 0, stream,
                       k, text, mel, KPS_HI, KPS_LO);
    hipLaunchKernelGGL(score_kernel, dim3(2048), dim3(256), 0, stream,
                       q, PEQ, KPS_HI, KPS_LO, text, mel, align, IDX, CNT, FLG);
    hipLaunchKernelGGL(refine_kernel, dim3(256), dim3(256), 0, stream,
                       q, k, text, mel, FLG, CNT, IDX);
    hipLaunchKernelGGL(compress_kernel, dim3(TDS / 128, NB), dim3(256), 0, stream,
                       v, wc, IDX, mel, out);
}

// Round 8
// 223.379 us; speedup vs baseline: 5.1268x; 1.0402x over previous
//
#include <hip/hip_runtime.h>
#include <math.h>

#define NB  32
#define TDS 2048
#define LL  512
#define DD  256
#define DC  64   // D/RATIO
#define GAP_THR 4e-4f

typedef __attribute__((ext_vector_type(8)))  short short8;
typedef __attribute__((ext_vector_type(16))) float f32x16;
typedef __attribute__((ext_vector_type(4)))  float f32x4;

__device__ __forceinline__ unsigned short f2bf(float x) {
    union { float f; unsigned u; } v; v.f = x;
    unsigned r = v.u + 0x7fffu + ((v.u >> 16) & 1u);
    return (unsigned short)(r >> 16);
}
__device__ __forceinline__ float bf2f(unsigned short h) {
    union { unsigned u; float f; } v; v.u = ((unsigned)h) << 16;
    return v.f;
}

// ---------------------------------------------------------------------------
// ws layout (bytes):
//   [0, 16777216)           : KPS  bf16 hi+lo of k+pe_k, MFMA-fragment order
//   [16777216, 18874368)    : PEQ  f32 (pe_q with w_s=1)
//   then NB*TDS ints IDX, 1 int CNT, NB*TDS ints FLAGS
// KPS fragment order: element (b, l=cs*32+lane32, k=ks*32+kh*16+g*8+j, plane):
//   byte = b*524288 + ks*65536 + cs*4096 + plane*2048 + kh*1024 + g*512
//        + lane32*16 + j*2
// A wave's B-fragment (plane,kh) for (ks,cs) = contiguous 1KB: lane l reads
//   16B at + (l>>5)*512 + (l&31)*16  -> one coalesced global_load_dwordx4.
// ---------------------------------------------------------------------------

__global__ void peq_kernel(float* __restrict__ peq, int* __restrict__ cnt) {
    int idx = blockIdx.x * 256 + threadIdx.x;        // < TDS*DD
    if (idx == 0) cnt[0] = 0;
    int t = idx >> 8;
    int d = idx & 255;
    int i = d >> 1;
    double invdiv = exp((double)i * (-9.210340371976184 / 128.0));
    double ang = (double)t * invdiv;
    double s, c;
    sincos(ang, &s, &c);
    peq[idx] = (float)((d & 1) ? c : s);
}

// k + pe_k, split into bf16 hi/lo planes, written in MFMA-fragment order.
__global__ __launch_bounds__(256)
void pek_kernel(const float* __restrict__ k,
                const int* __restrict__ text_lengths,
                const int* __restrict__ mel_lengths,
                char* __restrict__ kps) {
    __shared__ double invdiv[128];
    const int tid = threadIdx.x;
    if (tid < 128) invdiv[tid] = exp((double)tid * (-9.210340371976184 / 128.0));
    __syncthreads();
    int f = blockIdx.x * 256 + tid;                  // < NB*16384
    int b = f >> 14;
    int r = f & 16383;
    int ks = r >> 11;                                // 0..7
    int r2 = r & 2047;
    int cs = r2 >> 7;                                // 0..15
    int r3 = r2 & 127;
    int kh = r3 >> 6;                                // (khg layout: kh,g,lane32)
    int g  = (r3 >> 5) & 1;
    int lane32 = r3 & 31;
    int l  = cs * 32 + lane32;
    int k0 = ks * 32 + kh * 16 + g * 8;
    const float* kr = k + ((size_t)(b * LL + l)) * DD + k0;
    float4 kv0 = *(const float4*)(kr);
    float4 kv1 = *(const float4*)(kr + 4);
    float kv[8] = {kv0.x, kv0.y, kv0.z, kv0.w, kv1.x, kv1.y, kv1.z, kv1.w};
    double wsd = ((double)mel_lengths[b] * 0.25) / (double)text_lengths[b];
    double base_ang = wsd * (double)l;
    unsigned short h[8], lo8[8];
#pragma unroll
    for (int jj = 0; jj < 4; ++jj) {
        int i = (k0 >> 1) + jj;
        double ang = base_ang * invdiv[i];
        double n = rint(ang * 0.15915494309189535);
        double red = fma(n, -6.283185307179586, ang);   // |red| <= pi
        float sn, cs2;
        sincosf((float)red, &sn, &cs2);
        float e0 = kv[2 * jj] + sn;
        float e1 = kv[2 * jj + 1] + cs2;
        h[2 * jj]       = f2bf(e0);
        h[2 * jj + 1]   = f2bf(e1);
        lo8[2 * jj]     = f2bf(e0 - bf2f(h[2 * jj]));
        lo8[2 * jj + 1] = f2bf(e1 - bf2f(h[2 * jj + 1]));
    }
    size_t off = (size_t)b * 524288 + (size_t)ks * 65536 + (size_t)cs * 4096
               + kh * 1024 + g * 512 + lane32 * 16;
    uint4 hv, lv;
    hv.x = h[0] | ((unsigned)h[1] << 16); hv.y = h[2] | ((unsigned)h[3] << 16);
    hv.z = h[4] | ((unsigned)h[5] << 16); hv.w = h[6] | ((unsigned)h[7] << 16);
    lv.x = lo8[0] | ((unsigned)lo8[1] << 16); lv.y = lo8[2] | ((unsigned)lo8[3] << 16);
    lv.z = lo8[4] | ((unsigned)lo8[5] << 16); lv.w = lo8[6] | ((unsigned)lo8[7] << 16);
    *(uint4*)(kps + off) = hv;               // hi plane
    *(uint4*)(kps + off + 2048) = lv;        // lo plane
}

// ---------------------------------------------------------------------------
// score kernel: 32 t-rows x 512 l-cols per block, 256 threads = 4 waves.
// Wave wn owns cols [wn*128, wn*128+128) as 4 x 32-col fragments.
// B: direct L2->register fragment loads (KPS is L2-resident per XCD; no LDS,
// no barriers in the main loop). A: staged once to fragment-ordered LDS.
// ---------------------------------------------------------------------------
__global__ __launch_bounds__(256, 4)
void score_kernel(const float* __restrict__ q,
                  const float* __restrict__ peq,
                  const char* __restrict__ kps,
                  const int* __restrict__ text_lengths,
                  const int* __restrict__ mel_lengths,
                  float* __restrict__ align_out,
                  int* __restrict__ idx_out,
                  int* __restrict__ flag_cnt,
                  int* __restrict__ flags) {
    __shared__ alignas(16) char smA[32768];  // [ks8][plane2][kh2][g2][lane32][16B]
    struct Epi {
        float v1[4][32]; int i1[4][32]; float v2[4][32];
        float S[4][32];  float M[32];
    };
    __shared__ Epi ep;

    const int wgid = blockIdx.x;                 // 2048 blocks
    const int xcd = wgid & 7, loc = wgid >> 3;
    const int nid = xcd * 256 + loc;             // XCD-contiguous: 4 b's/XCD
    const int b  = nid >> 6;
    const int t0 = (nid & 63) << 5;              // 32-row tile

    const int tid = threadIdx.x;
    const int wn = tid >> 6, lane = tid & 63;
    const int c31 = lane & 31, hi5 = lane >> 5;
    const int tlen = text_lengths[b];
    const int melq = mel_lengths[b] >> 2;

    const char* kpb = kps + (size_t)b * 524288 + (size_t)(hi5 * 512 + c31 * 16);

    f32x16 acc[4];
#pragma unroll
    for (int ci = 0; ci < 4; ++ci)
#pragma unroll
        for (int rg = 0; rg < 16; ++rg) acc[ci][rg] = 0.f;

    // ---- B fragment loads: 1KB coalesced, L2-hit. dst[0..3]=bh0,bh1,bl0,bl1
#define BLOAD(dst, ksv, civ)                                                    \
    {                                                                           \
        const char* p = kpb + (ksv) * 65536 + (wn * 4 + (civ)) * 4096;          \
        dst[0] = *(const short8*)(p);                                           \
        dst[1] = *(const short8*)(p + 1024);                                    \
        dst[2] = *(const short8*)(p + 2048);                                    \
        dst[3] = *(const short8*)(p + 3072);                                    \
    }
#define MFMA6(CI, B)                                                            \
    {                                                                           \
        acc[CI] = __builtin_amdgcn_mfma_f32_32x32x16_bf16(ah0, B[0], acc[CI], 0, 0, 0); \
        acc[CI] = __builtin_amdgcn_mfma_f32_32x32x16_bf16(ah0, B[2], acc[CI], 0, 0, 0); \
        acc[CI] = __builtin_amdgcn_mfma_f32_32x32x16_bf16(al0, B[0], acc[CI], 0, 0, 0); \
        acc[CI] = __builtin_amdgcn_mfma_f32_32x32x16_bf16(ah1, B[1], acc[CI], 0, 0, 0); \
        acc[CI] = __builtin_amdgcn_mfma_f32_32x32x16_bf16(ah1, B[3], acc[CI], 0, 0, 0); \
        acc[CI] = __builtin_amdgcn_mfma_f32_32x32x16_bf16(al1, B[1], acc[CI], 0, 0, 0); \
    }

    short8 B0[4], B1[4];
    BLOAD(B0, 0, 0)                              // issue before the A barrier

    // ---- A staging: q+peq -> hi/lo fragment-order LDS (once) ----
    {
        const int sr = tid >> 3, kc = tid & 7;
        const float* qr = q   + ((size_t)(b * TDS) + t0 + sr) * DD;
        const float* pr = peq + (size_t)(t0 + sr) * DD;
#pragma unroll
        for (int kq = 0; kq < 4; ++kq) {
            int m = kq * 8 + kc;                 // 8-elem chunk index, k=m*8+j
            int k0 = m * 8;
            float4 qa = *(const float4*)(qr + k0);
            float4 qb4 = *(const float4*)(qr + k0 + 4);
            float4 pa = *(const float4*)(pr + k0);
            float4 pb = *(const float4*)(pr + k0 + 4);
            float e[8] = {(qa.x + pa.x) * 0.0625f, (qa.y + pa.y) * 0.0625f,
                          (qa.z + pa.z) * 0.0625f, (qa.w + pa.w) * 0.0625f,
                          (qb4.x + pb.x) * 0.0625f, (qb4.y + pb.y) * 0.0625f,
                          (qb4.z + pb.z) * 0.0625f, (qb4.w + pb.w) * 0.0625f};
            unsigned short h[8], lo[8];
#pragma unroll
            for (int j = 0; j < 8; ++j) {
                h[j] = f2bf(e[j]);
                lo[j] = f2bf(e[j] - bf2f(h[j]));
            }
            uint4 hv, lv;
            hv.x = h[0] | ((unsigned)h[1] << 16); hv.y = h[2] | ((unsigned)h[3] << 16);
            hv.z = h[4] | ((unsigned)h[5] << 16); hv.w = h[6] | ((unsigned)h[7] << 16);
            lv.x = lo[0] | ((unsigned)lo[1] << 16); lv.y = lo[2] | ((unsigned)lo[3] << 16);
            lv.z = lo[4] | ((unsigned)lo[5] << 16); lv.w = lo[6] | ((unsigned)lo[7] << 16);
            int base = (m >> 2) * 4096 + ((m >> 1) & 1) * 1024 + (m & 1) * 512 + sr * 16;
            *(uint4*)(smA + base) = hv;          // plane 0 (hi)
            *(uint4*)(smA + base + 2048) = lv;   // plane 1 (lo)
        }
    }
    __syncthreads();                             // the only pre-epilogue barrier

    const int afr = hi5 * 512 + c31 * 16;
    for (int ks = 0; ks < 8; ++ks) {
        const char* ab = smA + ks * 4096 + afr;
        short8 ah0 = *(const short8*)(ab);            // plane0 kh0
        short8 ah1 = *(const short8*)(ab + 1024);     // plane0 kh1
        short8 al0 = *(const short8*)(ab + 2048);     // plane1 kh0
        short8 al1 = *(const short8*)(ab + 3072);     // plane1 kh1
        // ci0: compute B0, prefetch ci1->B1
        BLOAD(B1, ks, 1)
        MFMA6(0, B0)
        // ci1: compute B1, prefetch ci2->B0
        BLOAD(B0, ks, 2)
        MFMA6(1, B1)
        // ci2: compute B0, prefetch ci3->B1
        BLOAD(B1, ks, 3)
        MFMA6(2, B0)
        // ci3: compute B1, prefetch (ks+1,0)->B0
        if (ks < 7) BLOAD(B0, ks + 1, 0)
        MFMA6(3, B1)
    }
#undef BLOAD
#undef MFMA6

    // ---- epilogue: mask, top-2, softmax, stores (32x32 C layout:
    //      col = wn*128 + ci*32 + c31, row = (rg&3)+8*(rg>>2)+4*hi5) ----
    const float NEGINF = -__builtin_inff();
#pragma unroll
    for (int ci = 0; ci < 4; ++ci) {
        int col = wn * 128 + ci * 32 + c31;
        if (col >= tlen) {
#pragma unroll
            for (int rg = 0; rg < 16; ++rg) acc[ci][rg] = NEGINF;
        }
    }
    float v1[16]; int i1[16]; float v2[16];
#pragma unroll
    for (int rg = 0; rg < 16; ++rg) {
        v1[rg] = acc[0][rg]; i1[rg] = wn * 128 + c31; v2[rg] = NEGINF;
#pragma unroll
        for (int ci = 1; ci < 4; ++ci) {
            float v = acc[ci][rg]; int col = wn * 128 + ci * 32 + c31;
            if (v > v1[rg]) { v2[rg] = v1[rg]; v1[rg] = v; i1[rg] = col; }
            else if (v > v2[rg]) v2[rg] = v;
        }
    }
#pragma unroll
    for (int off = 1; off <= 16; off <<= 1) {
#pragma unroll
        for (int rg = 0; rg < 16; ++rg) {
            float ov1 = __shfl_xor(v1[rg], off, 64);
            int   oi1 = __shfl_xor(i1[rg], off, 64);
            float ov2 = __shfl_xor(v2[rg], off, 64);
            if (ov1 > v1[rg]) { v2[rg] = fmaxf(v1[rg], ov2); v1[rg] = ov1; i1[rg] = oi1; }
            else if (ov1 < v1[rg]) { v2[rg] = fmaxf(v2[rg], ov1); }
            else { i1[rg] = min(i1[rg], oi1); v2[rg] = v1[rg]; }
        }
    }
    if (c31 == 0) {
#pragma unroll
        for (int rg = 0; rg < 16; ++rg) {
            int r32 = (rg & 3) + 8 * (rg >> 2) + 4 * hi5;
            ep.v1[wn][r32] = v1[rg]; ep.i1[wn][r32] = i1[rg]; ep.v2[wn][r32] = v2[rg];
        }
    }
    __syncthreads();
    {
        const int r32 = c31;
        float V1 = ep.v1[0][r32]; int I1 = ep.i1[0][r32]; float V2 = ep.v2[0][r32];
#pragma unroll
        for (int w = 1; w < 4; ++w) {
            float cv1 = ep.v1[w][r32]; int ci1 = ep.i1[w][r32]; float cv2 = ep.v2[w][r32];
            if (cv1 > V1) { V2 = fmaxf(V1, cv2); V1 = cv1; I1 = ci1; }
            else if (cv1 < V1) { V2 = fmaxf(V2, cv1); }
            else { V2 = V1; }
        }
        if (wn == 0 && hi5 == 0) {
            int t = t0 + r32;
            idx_out[b * TDS + t] = I1;
            if (t < melq && (V1 - V2) < GAP_THR) {
                int pos = atomicAdd(flag_cnt, 1);
                flags[pos] = (b << 11) | t;
            }
            ep.M[r32] = V1;
        }
    }
    __syncthreads();
    float ssum[16];
#pragma unroll
    for (int rg = 0; rg < 16; ++rg) {
        int r32 = (rg & 3) + 8 * (rg >> 2) + 4 * hi5;
        float M = ep.M[r32];
        float s = 0.f;
#pragma unroll
        for (int ci = 0; ci < 4; ++ci) {
            float p = __expf(acc[ci][rg] - M);
            acc[ci][rg] = p; s += p;
        }
        ssum[rg] = s;
    }
#pragma unroll
    for (int off = 1; off <= 16; off <<= 1)
#pragma unroll
        for (int rg = 0; rg < 16; ++rg) ssum[rg] += __shfl_xor(ssum[rg], off, 64);
    if (c31 == 0) {
#pragma unroll
        for (int rg = 0; rg < 16; ++rg) {
            int r32 = (rg & 3) + 8 * (rg >> 2) + 4 * hi5;
            ep.S[wn][r32] = ssum[rg];
        }
    }
    __syncthreads();
#pragma unroll
    for (int rg = 0; rg < 16; ++rg) {
        int r32 = (rg & 3) + 8 * (rg >> 2) + 4 * hi5;
        int t = t0 + r32;
        float denom = ep.S[0][r32] + ep.S[1][r32] + ep.S[2][r32] + ep.S[3][r32];
        float sc = (t < melq) ? (1.0f / denom) : 0.f;
        size_t obase = ((size_t)(b * TDS + t)) * LL + wn * 128 + c31;
#pragma unroll
        for (int ci = 0; ci < 4; ++ci)
            __builtin_nontemporal_store(acc[ci][rg] * sc, align_out + obase + ci * 32);
    }
}

// ---------------------------------------------------------------------------
// refine kernel: recompute flagged rows' 512 scores fully in f64, fix idx.
// ---------------------------------------------------------------------------
__global__ __launch_bounds__(256)
void refine_kernel(const float* __restrict__ q,
                   const float* __restrict__ k,
                   const int* __restrict__ text_lengths,
                   const int* __restrict__ mel_lengths,
                   const int* __restrict__ flags,
                   const int* __restrict__ flag_cnt,
                   int* __restrict__ idx_out) {
    __shared__ double qd[DD];
    __shared__ double invdiv[128];
    __shared__ double rbest[4];
    __shared__ int    ribest[4];
    const int tid = threadIdx.x;
    if (tid < 128)
        invdiv[tid] = 1.0 / pow(10000.0, (double)tid * (1.0 / 128.0));
    const int cnt = flag_cnt[0];
    for (int r = blockIdx.x; r < cnt; r += gridDim.x) {
        const int code = flags[r];
        const int b = code >> 11, t = code & 2047;
        const int tlen = text_lengths[b];
        const double ws = ((double)mel_lengths[b] * 0.25) / (double)text_lengths[b];
        __syncthreads();
        {
            const int d = tid, i = d >> 1;
            double ang = (double)t * invdiv[i];
            double sn, cs;
            sincos(ang, &sn, &cs);
            qd[d] = ((double)q[((size_t)b * TDS + t) * DD + d] + ((d & 1) ? cs : sn)) * 0.0625;
        }
        __syncthreads();
        double best = -1.0e300; int bi = 0x7fffffff;
        for (int p = 0; p < 2; ++p) {
            const int l = tid + p * 256;
            if (l < tlen) {
                const float* kr = k + ((size_t)b * LL + l) * DD;
                const double wl = ws * (double)l;
                double sacc = 0.0;
                for (int i = 0; i < 128; ++i) {
                    double ang = wl * invdiv[i];
                    double sn, cs;
                    sincos(ang, &sn, &cs);
                    sacc += ((double)kr[2 * i]     + sn) * qd[2 * i];
                    sacc += ((double)kr[2 * i + 1] + cs) * qd[2 * i + 1];
                }
                if (sacc > best || (sacc == best && l < bi)) { best = sacc; bi = l; }
            }
        }
        for (int off = 1; off <= 32; off <<= 1) {
            double ov = __shfl_xor(best, off, 64);
            int   oi = __shfl_xor(bi, off, 64);
            if (ov > best || (ov == best && oi < bi)) { best = ov; bi = oi; }
        }
        const int wv = tid >> 6;
        if ((tid & 63) == 0) { rbest[wv] = best; ribest[wv] = bi; }
        __syncthreads();
        if (tid == 0) {
            double bb = rbest[0]; int ii = ribest[0];
            for (int w = 1; w < 4; ++w)
                if (rbest[w] > bb || (rbest[w] == bb && ribest[w] < ii)) { bb = rbest[w]; ii = ribest[w]; }
            idx_out[b * TDS + t] = ii;
        }
    }
}

// ---------------------------------------------------------------------------
// compress kernel: out[b,c,t] = sum_d w[c,d] * v[b, idx[b,t], d] (0 if masked)
// ---------------------------------------------------------------------------
__global__ __launch_bounds__(256, 4)
void compress_kernel(const float* __restrict__ v,
                     const float* __restrict__ wc,
                     const int* __restrict__ idx_in,
                     const int* __restrict__ mel_lengths,
                     float* __restrict__ out) {
    __shared__ float Ws[256 * 68];
    __shared__ float Vs[16 * 132];
    __shared__ int   idxs[128];
    const int b   = blockIdx.y;
    const int t0  = blockIdx.x * 128;
    const int tid = threadIdx.x;
    const int melq = mel_lengths[b] >> 2;
    const float* vb = v + (size_t)b * LL * DD;

    if (tid < 128) {
        int t = t0 + tid;
        int ii = idx_in[b * TDS + t];
        idxs[tid] = (t >= melq) ? -1 : ii;
    }
#pragma unroll
    for (int r = 0; r < 16; ++r) {
        int f = tid + r * 256;
        int c = f >> 6;
        int u = f & 63;
        float4 wv = *(const float4*)(wc + (size_t)c * DD + u * 4);
        Ws[(u * 4 + 0) * 68 + c] = wv.x;
        Ws[(u * 4 + 1) * 68 + c] = wv.y;
        Ws[(u * 4 + 2) * 68 + c] = wv.z;
        Ws[(u * 4 + 3) * 68 + c] = wv.w;
    }

    const int tx = tid & 7;
    const int ty = tid >> 3;
    const int tv = tid >> 2;
    const int uv = tid & 3;
    float acc[8][4];
#pragma unroll
    for (int i = 0; i < 8; ++i)
#pragma unroll
        for (int j = 0; j < 4; ++j) acc[i][j] = 0.f;

    for (int ks = 0; ks < 16; ++ks) {
        const int d0 = ks * 16;
        __syncthreads();
#pragma unroll
        for (int p = 0; p < 2; ++p) {
            int t = tv + p * 64;
            int row = idxs[t];
            float4 vv = make_float4(0.f, 0.f, 0.f, 0.f);
            if (row >= 0) vv = *(const float4*)(vb + (size_t)row * DD + d0 + uv * 4);
            Vs[(uv * 4 + 0) * 132 + t] = vv.x;
            Vs[(uv * 4 + 1) * 132 + t] = vv.y;
            Vs[(uv * 4 + 2) * 132 + t] = vv.z;
            Vs[(uv * 4 + 3) * 132 + t] = vv.w;
        }
        __syncthreads();
#pragma unroll
        for (int kk = 0; kk < 16; ++kk) {
            const float* wrow = Ws + (size_t)(d0 + kk) * 68 + tx * 8;
            float4 a0 = *(const float4*)(wrow);
            float4 a1 = *(const float4*)(wrow + 4);
            float4 bb = *(const float4*)(Vs + kk * 132 + ty * 4);
            const float av[8] = {a0.x, a0.y, a0.z, a0.w, a1.x, a1.y, a1.z, a1.w};
            const float bv[4] = {bb.x, bb.y, bb.z, bb.w};
#pragma unroll
            for (int i = 0; i < 8; ++i)
#pragma unroll
                for (int j = 0; j < 4; ++j)
                    acc[i][j] = fmaf(av[i], bv[j], acc[i][j]);
        }
    }
#pragma unroll
    for (int ci = 0; ci < 8; ++ci) {
        int c = tx * 8 + ci;
        f32x4 o = {acc[ci][0], acc[ci][1], acc[ci][2], acc[ci][3]};
        __builtin_nontemporal_store(o, (f32x4*)(out + ((size_t)(b * DC + c)) * TDS + t0 + ty * 4));
    }
}

extern "C" void kernel_launch(void* const* d_in, const int* in_sizes, int n_in,
                              void* d_out, int out_size, void* d_ws, size_t ws_size,
                              hipStream_t stream) {
    const float* q    = (const float*)d_in[0];
    const float* k    = (const float*)d_in[1];
    const float* v    = (const float*)d_in[2];
    const float* wc   = (const float*)d_in[3];
    const int*   text = (const int*)d_in[4];
    const int*   mel  = (const int*)d_in[5];

    float* out   = (float*)d_out;
    float* align = out + (size_t)NB * DC * TDS;

    char*  wsb = (char*)d_ws;
    char*  KPS = wsb;
    float* PEQ = (float*)(wsb + 16777216);
    int*   IDX = (int*)(wsb + 16777216 + 2097152);
    int*   CNT = IDX + (size_t)NB * TDS;
    int*   FLG = CNT + 1;

    hipLaunchKernelGGL(peq_kernel, dim3(TDS * DD / 256), dim3(256), 0, stream, PEQ, CNT);
    hipLaunchKernelGGL(pek_kernel, dim3(NB * 16384 / 256), dim3(256), 0, stream,
                       k, text, mel, KPS);
    hipLaunchKernelGGL(score_kernel, dim3(2048), dim3(256), 0, stream,
                       q, PEQ, KPS, text, mel, align, IDX, CNT, FLG);
    hipLaunchKernelGGL(refine_kernel, dim3(256), dim3(256), 0, stream,
                       q, k, text, mel, FLG, CNT, IDX);
    hipLaunchKernelGGL(compress_kernel, dim3(TDS / 128, NB), dim3(256), 0, stream,
                       v, wc, IDX, mel, out);
}